// Round 8
// baseline (156.521 us; speedup 1.0000x reference)
//
#include <hip/hip_runtime.h>
#include <hip/hip_bf16.h>

#define TB 64     // batches
#define SL 512    // MAX_LEN (all sequences full length)
#define DIM 1024  // feature dim
#define LAT 512   // latent dim

// Tiled bf16 row-block stride in ELEMENTS (16 rows x 1024 cols = 16384 + 256 pad).
#define RBS 16640

typedef short short8 __attribute__((ext_vector_type(8)));
typedef unsigned uint4v __attribute__((ext_vector_type(4)));
typedef float f32x4 __attribute__((ext_vector_type(4)));

__device__ inline unsigned bfr(float f) {   // fp32 -> bf16 bits (RNE), low 16
    unsigned u = __builtin_bit_cast(unsigned, f);
    u += 0x7FFFu + ((u >> 16) & 1u);
    return u >> 16;
}
__device__ inline unsigned pk2(float lo, float hi) {   // pack 2 bf16 into u32
    return bfr(lo) | (bfr(hi) << 16);
}

// ============================================================================
// Tiled bf16 layout: T[rb][cb][16][32], rb = row/16 (2048), cb = col/32 (32).
// One 16x32 tile (1KB) == one MFMA A/B fragment. addr = rb*RBS + cb*512 + r*32+c
// ============================================================================

// K0: fp32 row-major -> bf16 tiled. Block g handles rows g*16..g*16+15.
__global__ __launch_bounds__(256) void k0_convert(const float* __restrict__ seq,
                                                  unsigned short* __restrict__ tb) {
    const int gblk = blockIdx.x;          // 2048 row-groups
    const int tid = threadIdx.x;
    const float* src = seq + (size_t)gblk * 16 * DIM;
    unsigned short* dst = tb + (size_t)gblk * RBS;
    const int cb = tid >> 3;              // tile column 0..31
    const int cc = (tid & 7) * 4;         // col within tile
#pragma unroll
    for (int j = 0; j < 16; ++j) {
        float4 v = *(const float4*)(src + (size_t)j * DIM + tid * 4);
        unsigned short* d = dst + cb * 512 + j * 32 + cc;
        uint2 w;
        w.x = pk2(v.x, v.y);
        w.y = pk2(v.z, v.w);
        *(uint2*)d = w;
    }
}

// Async 1KB tile copy: per-lane global src (16B granules), wave-uniform LDS dst.
#define GLDS(srcp, dstp)                                                          \
    __builtin_amdgcn_global_load_lds(                                             \
        (const __attribute__((address_space(1))) void*)(srcp),                    \
        (__attribute__((address_space(3))) void*)(dstp), 16, 0, 0)

// K1 v5: per-(batch, 64-q-row tile) block, 512 threads (8 waves).
// Wave w owns k cols {nb*128 + w*16}; all 64 q rows. The 8 waves' K staging
// covers ALL 32 row-blocks of the batch per ds-chunk, so Q fragments read
// from K_lds too (row-blocks qt*4+mt) -> uniform 4 loads/wave/stage.
// 3-buffer rotation, depth-2 prefetch, counted s_waitcnt vmcnt(4) + raw
// s_barrier per stage (loads stay in flight across barriers; no vmcnt(0)
// drain in the main loop).
__global__ __launch_bounds__(512) void k1_scores(const unsigned short* __restrict__ tb,
                                                 float* __restrict__ c_part) {
    const int blk = blockIdx.x;            // 512 = 8 q-tiles * 64 batches
    const int b = blk & 63, qt = blk >> 6; // same-batch tiles co-XCD
    const int tid = threadIdx.x;
    const int w = tid >> 6, lane = tid & 63;
    const int g = lane >> 4, l15 = lane & 15;
    const int qt4 = qt * 4;

    __shared__ __align__(16) unsigned short K_lds[3][32 * 512];  // 3 x 32 KB
    __shared__ float lred[64][8];
    __shared__ float invl[64];

    // staging: lane's swizzled source granule (elems); involution i^(i>>3)
    const int gsw = (lane ^ (lane >> 3)) * 8;
    // reading: swizzled byte offset within a 1KB tile for this lane's fragment
    const int tg = l15 * 4 + g;
    const int roff = (tg ^ (tg >> 3)) * 16;

    const unsigned short* krb = tb + (size_t)(b * 32 + w) * RBS + gsw;  // +nb*8*RBS

    f32x4 acc[4][4];   // [nb][mt]
#pragma unroll
    for (int nb = 0; nb < 4; ++nb)
#pragma unroll
        for (int mt = 0; mt < 4; ++mt) acc[nb][mt] = (f32x4){0.f, 0.f, 0.f, 0.f};

#define STAGE(bufi, ds_) {                                                        \
    _Pragma("unroll") for (int nb = 0; nb < 4; ++nb)                              \
        GLDS(krb + (size_t)(nb * 8) * RBS + (ds_) * 512,                          \
             &K_lds[bufi][(nb * 8 + w) * 512]);                                   \
}
#define COMPUTE(bufi) {                                                           \
    const char* Kc = (const char*)K_lds[bufi];                                    \
    short8 qf[4], kf[4];                                                          \
    _Pragma("unroll") for (int mt = 0; mt < 4; ++mt)                              \
        qf[mt] = *(const short8*)(Kc + (qt4 + mt) * 1024 + roff);                 \
    _Pragma("unroll") for (int nb = 0; nb < 4; ++nb)                              \
        kf[nb] = *(const short8*)(Kc + ((nb << 3) + w) * 1024 + roff);            \
    _Pragma("unroll") for (int nb = 0; nb < 4; ++nb)                              \
        _Pragma("unroll") for (int mt = 0; mt < 4; ++mt)                          \
            acc[nb][mt] = __builtin_amdgcn_mfma_f32_16x16x32_bf16(                \
                qf[mt], kf[nb], acc[nb][mt], 0, 0, 0);                            \
}

    // prologue: stages 0 and 1 in flight (8 outstanding loads/wave)
    STAGE(0, 0);
    STAGE(1, 1);

    for (int ds = 0; ds < 30; ++ds) {
        asm volatile("s_waitcnt vmcnt(4)" ::: "memory");   // stage ds landed (mine)
        __builtin_amdgcn_s_barrier();                      // all waves' stage ds landed
        asm volatile("" ::: "memory");
        __builtin_amdgcn_sched_barrier(0);
        STAGE((ds + 2) % 3, ds + 2);                       // refill; 8 outstanding again
        COMPUTE(ds % 3);
    }
    // ds = 30: no refill; outstanding = S30(4)+S31(4)
    asm volatile("s_waitcnt vmcnt(4)" ::: "memory");
    __builtin_amdgcn_s_barrier();
    asm volatile("" ::: "memory");
    __builtin_amdgcn_sched_barrier(0);
    COMPUTE(0);   // 30 % 3
    // ds = 31: outstanding = S31(4)
    asm volatile("s_waitcnt vmcnt(0)" ::: "memory");
    __builtin_amdgcn_s_barrier();
    asm volatile("" ::: "memory");
    __builtin_amdgcn_sched_barrier(0);
    COMPUTE(1);   // 31 % 3
#undef STAGE
#undef COMPUTE

    // exp (scale 1/32); q = mt*16 + g*4 + r, k = nb*128 + w*16 + l15
#pragma unroll
    for (int nb = 0; nb < 4; ++nb)
#pragma unroll
        for (int mt = 0; mt < 4; ++mt) {
            f32x4 t = acc[nb][mt];
#pragma unroll
            for (int r = 0; r < 4; ++r) t[r] = __expf(t[r] * 0.03125f);
            acc[nb][mt] = t;
        }

    // row sums: per-thread over nb, then over the 16-lane l15 group
    float rp[4][4];
#pragma unroll
    for (int mt = 0; mt < 4; ++mt)
#pragma unroll
        for (int r = 0; r < 4; ++r) {
            float s = 0.f;
#pragma unroll
            for (int nb = 0; nb < 4; ++nb) s += acc[nb][mt][r];
            rp[mt][r] = s;
        }
#pragma unroll
    for (int m = 1; m <= 8; m <<= 1)
#pragma unroll
        for (int mt = 0; mt < 4; ++mt)
#pragma unroll
            for (int r = 0; r < 4; ++r)
                rp[mt][r] += __shfl_xor(rp[mt][r], m, 64);
    if (l15 == 0) {
#pragma unroll
        for (int mt = 0; mt < 4; ++mt)
#pragma unroll
            for (int r = 0; r < 4; ++r)
                lred[mt * 16 + g * 4 + r][w] = rp[mt][r];
    }
    __syncthreads();
    if (tid < 64) {
        float l = 0.f;
#pragma unroll
        for (int ww = 0; ww < 8; ++ww) l += lred[tid][ww];
        invl[tid] = 1.0f / l;
    }
    __syncthreads();

    float iq[4][4];
#pragma unroll
    for (int mt = 0; mt < 4; ++mt)
#pragma unroll
        for (int r = 0; r < 4; ++r)
            iq[mt][r] = invl[mt * 16 + g * 4 + r];

    // weighted column sums over this block's 64 q rows
#pragma unroll
    for (int nb = 0; nb < 4; ++nb) {
        float cp = 0.f;
#pragma unroll
        for (int mt = 0; mt < 4; ++mt)
#pragma unroll
            for (int r = 0; r < 4; ++r) cp += acc[nb][mt][r] * iq[mt][r];
        cp += __shfl_xor(cp, 16, 64);
        cp += __shfl_xor(cp, 32, 64);
        if (lane < 16)
            c_part[(size_t)blk * 512 + nb * 128 + w * 16 + lane] = cp;
    }
}

// K2: pooled_part from the bf16 tiled buffer.
__global__ __launch_bounds__(256) void k2_pool(const unsigned short* __restrict__ tb,
                                               const float* __restrict__ c_part,
                                               float* __restrict__ pooled_part) {
    const int blk = blockIdx.x;          // 256 = 64 batches * 4 key-ranges
    const int b = blk >> 2, kt = blk & 3;
    const int tid = threadIdx.x;
    __shared__ float cw[128];
    if (tid < 128) {
        int k = kt * 128 + tid;
        float s = 0.f;
#pragma unroll
        for (int qt = 0; qt < 8; ++qt) s += c_part[(size_t)(qt * 64 + b) * 512 + k];
        cw[tid] = s;
    }
    __syncthreads();
    const int cb = tid >> 3;              // d/32
    const int cc = (tid & 7) * 4;         // d%32
    float a0 = 0.f, a1 = 0.f, a2 = 0.f, a3 = 0.f;
    const unsigned short* base = tb + (size_t)(b * 32 + kt * 8) * RBS + cb * 512 + cc;
    for (int kk = 0; kk < 128; ++kk) {
        float c = cw[kk];
        const unsigned short* p = base + (size_t)(kk >> 4) * RBS + (kk & 15) * 32;
        uint2 u = *(const uint2*)p;
        a0 += c * __builtin_bit_cast(float, u.x << 16);
        a1 += c * __builtin_bit_cast(float, u.x & 0xFFFF0000u);
        a2 += c * __builtin_bit_cast(float, u.y << 16);
        a3 += c * __builtin_bit_cast(float, u.y & 0xFFFF0000u);
    }
    float* dst = pooled_part + (size_t)(b * 4 + kt) * DIM + tid * 4;
    *(float4*)dst = make_float4(a0, a1, a2, a3);
}

// K3: out = pooled @ W + bias for both heads. out: [mean(64x512), log_var(64x512)]
__global__ __launch_bounds__(256) void k3_out(const float* __restrict__ pooled_part,
                                              const float* __restrict__ Wm,
                                              const float* __restrict__ bm,
                                              const float* __restrict__ Wv,
                                              const float* __restrict__ bv,
                                              float* __restrict__ out) {
    const int blk = blockIdx.x;          // 128 = 64 batches * 2 heads
    const int b = blk >> 1, which = blk & 1;
    const int tid = threadIdx.x;
    const float* W = which ? Wv : Wm;
    const float* bias = which ? bv : bm;
    __shared__ float p[1024];
#pragma unroll
    for (int i = 0; i < 4; ++i) {
        int d = tid + (i << 8);
        float s = 0.f;
#pragma unroll
        for (int kt = 0; kt < 4; ++kt) s += pooled_part[(size_t)(b * 4 + kt) * DIM + d];
        p[d] = s;
    }
    __syncthreads();
    float acc0 = bias[tid], acc1 = bias[tid + 256];
    for (int d = 0; d < 1024; ++d) {
        float pv = p[d];
        const float* wr = W + (size_t)d * LAT;
        acc0 += pv * wr[tid];
        acc1 += pv * wr[tid + 256];
    }
    float* o = out + (size_t)which * TB * LAT + (size_t)b * LAT;
    o[tid] = acc0;
    o[tid + 256] = acc1;
}

// ============================ fallback path (round-3) =======================
__device__ inline short8 ldfrag_f(const char* lds, int row, int kk, int g) {
    int byte = (row * 256 + kk * 64 + (g << 4)) ^ ((row & 7) << 4);
    return *(const short8*)(lds + byte);
}
__device__ inline void stage_load_f(const float* src, float4* gg) {
    gg[0] = *(const float4*)(src);
    gg[1] = *(const float4*)(src + 4);
    gg[2] = *(const float4*)(src + 8);
    gg[3] = *(const float4*)(src + 12);
}
__device__ inline void stage_write_f(char* lds, int t, const float4* gg) {
    int r = t >> 3;
    int x0 = (t & 7) * 32;
    int sw = (r & 7) << 4;
    uint4v w0, w1;
    w0[0] = pk2(gg[0].x, gg[0].y); w0[1] = pk2(gg[0].z, gg[0].w);
    w0[2] = pk2(gg[1].x, gg[1].y); w0[3] = pk2(gg[1].z, gg[1].w);
    w1[0] = pk2(gg[2].x, gg[2].y); w1[1] = pk2(gg[2].z, gg[2].w);
    w1[2] = pk2(gg[3].x, gg[3].y); w1[3] = pk2(gg[3].z, gg[3].w);
    *(uint4v*)(lds + ((r * 256 + x0) ^ sw))      = w0;
    *(uint4v*)(lds + ((r * 256 + x0 + 16) ^ sw)) = w1;
}
__global__ __launch_bounds__(512, 2) void k1_scores_fb(const float* __restrict__ seq,
                                                       float* __restrict__ c_part) {
    const int blk = blockIdx.x;
    const int b = blk & 63, qt = blk >> 6;
    const int tid = threadIdx.x;
    const int wave = tid >> 6, lane = tid & 63;
    const int qh = wave >> 2, kq = wave & 3;
    const int g = lane >> 4, l15 = lane & 15;
    __shared__ __align__(16) char Qb[16384];
    __shared__ __align__(16) char Kb[2][16384];
    __shared__ float lred[64][4];
    __shared__ float invl[64];
    __shared__ float cred[2][512];
    const float* qbase = seq + (size_t)(b * SL + qt * 64) * DIM;
    const float* kbase = seq + (size_t)(b * SL) * DIM;
    const int sr = tid >> 3;
    const int sx = (tid & 7) * 16;
    f32x4 acc[8][2];
#pragma unroll
    for (int nb = 0; nb < 8; ++nb)
#pragma unroll
        for (int mt = 0; mt < 2; ++mt) acc[nb][mt] = (f32x4){0.f, 0.f, 0.f, 0.f};
    {
        float4 gq[4], gk[4];
        stage_load_f(qbase + (size_t)sr * DIM + sx, gq);
        stage_load_f(kbase + (size_t)sr * DIM + sx, gk);
        stage_write_f(Qb, tid, gq);
        stage_write_f(Kb[0], tid, gk);
        __syncthreads();
    }
    for (int ds = 0; ds < 8; ++ds) {
        short8 qf[2][4];
#pragma unroll
        for (int mt = 0; mt < 2; ++mt)
#pragma unroll
            for (int kk = 0; kk < 4; ++kk)
                qf[mt][kk] = ldfrag_f(Qb, qh * 32 + mt * 16 + l15, kk, g);
#pragma unroll
        for (int nb = 0; nb < 8; ++nb) {
            const char* Kc = Kb[nb & 1];
            float4 gk[4], gq[4];
            if (nb < 7) {
                stage_load_f(kbase + (size_t)((nb + 1) * 64 + sr) * DIM + ds * 128 + sx, gk);
            } else if (ds < 7) {
                stage_load_f(kbase + (size_t)sr * DIM + (ds + 1) * 128 + sx, gk);
                stage_load_f(qbase + (size_t)sr * DIM + (ds + 1) * 128 + sx, gq);
            }
            short8 bf[4];
#pragma unroll
            for (int kk = 0; kk < 4; ++kk) bf[kk] = ldfrag_f(Kc, kq * 16 + l15, kk, g);
#pragma unroll
            for (int mt = 0; mt < 2; ++mt)
#pragma unroll
                for (int kk = 0; kk < 4; ++kk)
                    acc[nb][mt] = __builtin_amdgcn_mfma_f32_16x16x32_bf16(
                        qf[mt][kk], bf[kk], acc[nb][mt], 0, 0, 0);
            __syncthreads();
            if (nb < 7) {
                stage_write_f(Kb[(nb + 1) & 1], tid, gk);
            } else if (ds < 7) {
                stage_write_f(Kb[0], tid, gk);
                stage_write_f(Qb, tid, gq);
            }
            __syncthreads();
        }
    }
#pragma unroll
    for (int nb = 0; nb < 8; ++nb)
#pragma unroll
        for (int mt = 0; mt < 2; ++mt) {
            f32x4 t = acc[nb][mt];
#pragma unroll
            for (int r = 0; r < 4; ++r) t[r] = __expf(t[r] * 0.03125f);
            acc[nb][mt] = t;
        }
    float rp[2][4];
#pragma unroll
    for (int mt = 0; mt < 2; ++mt)
#pragma unroll
        for (int r = 0; r < 4; ++r) {
            float s = 0.f;
#pragma unroll
            for (int nb = 0; nb < 8; ++nb) s += acc[nb][mt][r];
            rp[mt][r] = s;
        }
#pragma unroll
    for (int m = 1; m <= 8; m <<= 1)
#pragma unroll
        for (int mt = 0; mt < 2; ++mt)
#pragma unroll
            for (int r = 0; r < 4; ++r)
                rp[mt][r] += __shfl_xor(rp[mt][r], m, 64);
    if (l15 == 0) {
#pragma unroll
        for (int mt = 0; mt < 2; ++mt)
#pragma unroll
            for (int r = 0; r < 4; ++r)
                lred[qh * 32 + mt * 16 + g * 4 + r][kq] = rp[mt][r];
    }
    __syncthreads();
    if (tid < 64) {
        float l = lred[tid][0] + lred[tid][1] + lred[tid][2] + lred[tid][3];
        invl[tid] = 1.0f / l;
    }
    __syncthreads();
    float iq[2][4];
#pragma unroll
    for (int mt = 0; mt < 2; ++mt)
#pragma unroll
        for (int r = 0; r < 4; ++r)
            iq[mt][r] = invl[qh * 32 + mt * 16 + g * 4 + r];
#pragma unroll
    for (int nb = 0; nb < 8; ++nb) {
        float cp = 0.f;
#pragma unroll
        for (int mt = 0; mt < 2; ++mt)
#pragma unroll
            for (int r = 0; r < 4; ++r) cp += acc[nb][mt][r] * iq[mt][r];
        cp += __shfl_xor(cp, 16, 64);
        cp += __shfl_xor(cp, 32, 64);
        if (lane < 16) cred[qh][nb * 64 + kq * 16 + lane] = cp;
    }
    __syncthreads();
    c_part[(size_t)blk * 512 + tid] = cred[0][tid] + cred[1][tid];
}
__global__ __launch_bounds__(256) void k2_pool_fb(const float* __restrict__ seq,
                                                  const float* __restrict__ c_part,
                                                  float* __restrict__ pooled_part) {
    const int blk = blockIdx.x;
    const int b = blk >> 2, kt = blk & 3;
    const int tid = threadIdx.x;
    __shared__ float cw[128];
    if (tid < 128) {
        int k = kt * 128 + tid;
        float s = 0.f;
#pragma unroll
        for (int qt = 0; qt < 8; ++qt) s += c_part[(size_t)(qt * 64 + b) * 512 + k];
        cw[tid] = s;
    }
    __syncthreads();
    float a0 = 0.f, a1 = 0.f, a2 = 0.f, a3 = 0.f;
    const float* base = seq + ((size_t)b * SL + kt * 128) * DIM + tid * 4;
    for (int kk = 0; kk < 128; ++kk) {
        float c = cw[kk];
        float4 v = *(const float4*)(base + (size_t)kk * DIM);
        a0 += c * v.x; a1 += c * v.y; a2 += c * v.z; a3 += c * v.w;
    }
    float* dst = pooled_part + (size_t)(b * 4 + kt) * DIM + tid * 4;
    *(float4*)dst = make_float4(a0, a1, a2, a3);
}
// ============================================================================

extern "C" void kernel_launch(void* const* d_in, const int* in_sizes, int n_in,
                              void* d_out, int out_size, void* d_ws, size_t ws_size,
                              hipStream_t stream) {
    const float* seq = (const float*)d_in[0];
    const float* Wm  = (const float*)d_in[1];
    const float* bm  = (const float*)d_in[2];
    const float* Wv  = (const float*)d_in[3];
    const float* bv  = (const float*)d_in[4];
    float* out = (float*)d_out;

    const size_t TBELEMS = (size_t)2048 * RBS;               // padded tiled buf
    const size_t need = TBELEMS * 2 + (512 * 512 + 64 * 4 * DIM) * 4;

    if (ws_size >= need) {
        unsigned short* tbuf = (unsigned short*)d_ws;
        float* c_part      = (float*)((char*)d_ws + TBELEMS * 2);
        float* pooled_part = c_part + 512 * 512;
        hipLaunchKernelGGL(k0_convert, dim3(2048), dim3(256), 0, stream, seq, tbuf);
        hipLaunchKernelGGL(k1_scores,  dim3(512),  dim3(512), 0, stream, tbuf, c_part);
        hipLaunchKernelGGL(k2_pool,    dim3(256),  dim3(256), 0, stream, tbuf, c_part, pooled_part);
        hipLaunchKernelGGL(k3_out,     dim3(128),  dim3(256), 0, stream, pooled_part,
                           Wm, bm, Wv, bv, out);
    } else {
        float* c_part      = (float*)d_ws;
        float* pooled_part = c_part + 512 * 512;
        hipLaunchKernelGGL(k1_scores_fb, dim3(512), dim3(512), 0, stream, seq, c_part);
        hipLaunchKernelGGL(k2_pool_fb,   dim3(256), dim3(256), 0, stream, seq, c_part, pooled_part);
        hipLaunchKernelGGL(k3_out,       dim3(128), dim3(256), 0, stream, pooled_part,
                           Wm, bm, Wv, bv, out);
    }
}

// Round 9
// 131.495 us; speedup vs baseline: 1.1903x; 1.1903x over previous
//
#include <hip/hip_runtime.h>
#include <hip/hip_bf16.h>

#define TB 64     // batches
#define SL 512    // MAX_LEN (all sequences full length)
#define DIM 1024  // feature dim
#define LAT 512   // latent dim

// Tiled bf16 row-block stride in ELEMENTS (16 rows x 1024 cols = 16384 + 256 pad).
#define RBS 16640

typedef short short8 __attribute__((ext_vector_type(8)));
typedef unsigned uint4v __attribute__((ext_vector_type(4)));
typedef float f32x4 __attribute__((ext_vector_type(4)));

__device__ inline unsigned bfr(float f) {   // fp32 -> bf16 bits (RNE), low 16
    unsigned u = __builtin_bit_cast(unsigned, f);
    u += 0x7FFFu + ((u >> 16) & 1u);
    return u >> 16;
}
__device__ inline unsigned pk2(float lo, float hi) {   // pack 2 bf16 into u32
    return bfr(lo) | (bfr(hi) << 16);
}

// ============================================================================
// Tiled bf16 layout: T[rb][cb][16][32], rb = row/16 (2048), cb = col/32 (32).
// One 16x32 tile (1KB) == one MFMA A/B fragment. addr = rb*RBS + cb*512 + r*32+c
// ============================================================================

// K0: fp32 row-major -> bf16 tiled. Block g handles rows g*16..g*16+15.
__global__ __launch_bounds__(256) void k0_convert(const float* __restrict__ seq,
                                                  unsigned short* __restrict__ tb) {
    const int gblk = blockIdx.x;          // 2048 row-groups
    const int tid = threadIdx.x;
    const float* src = seq + (size_t)gblk * 16 * DIM;
    unsigned short* dst = tb + (size_t)gblk * RBS;
    const int cb = tid >> 3;              // tile column 0..31
    const int cc = (tid & 7) * 4;         // col within tile
#pragma unroll
    for (int j = 0; j < 16; ++j) {
        float4 v = *(const float4*)(src + (size_t)j * DIM + tid * 4);
        unsigned short* d = dst + cb * 512 + j * 32 + cc;
        uint2 w;
        w.x = pk2(v.x, v.y);
        w.y = pk2(v.z, v.w);
        *(uint2*)d = w;
    }
}

// Async 1KB tile copy: per-lane global src (16B granules), wave-uniform LDS dst.
#define GLDS(srcp, dstp)                                                          \
    __builtin_amdgcn_global_load_lds(                                             \
        (const __attribute__((address_space(1))) void*)(srcp),                    \
        (__attribute__((address_space(3))) void*)(dstp), 16, 0, 0)

// K1 v6: per-(batch, 64-q-row tile) block, 512 threads (8 waves).
// Wave w owns k cols {nb*128 + w*16}; all 64 q rows. The 8 waves' K staging
// covers ALL 32 row-blocks of the batch per ds-chunk; Q fragments read from
// K_lds too (row-blocks qt*4+mt) -> uniform 4 loads/wave/stage.
// 2-buffer rotation with counted vmcnt (never 0 in the loop) and RAW
// s_barriers (no vmcnt drain). Since STAGE(ds+2) overwrites the buffer
// computed at ds, iteration is: vmcnt(4) | bar | COMPUTE | lgkmcnt(0) |
// bar | STAGE. LDS = 2x32KB + 2.3KB -> 2 blocks/CU (4 waves/SIMD).
__global__ __launch_bounds__(512, 4) void k1_scores(const unsigned short* __restrict__ tb,
                                                    float* __restrict__ c_part) {
    const int blk = blockIdx.x;            // 512 = 8 q-tiles * 64 batches
    const int b = blk & 63, qt = blk >> 6; // same-batch tiles co-XCD
    const int tid = threadIdx.x;
    const int w = tid >> 6, lane = tid & 63;
    const int g = lane >> 4, l15 = lane & 15;
    const int qt4 = qt * 4;

    __shared__ __align__(16) unsigned short K_lds[2][32 * 512];  // 2 x 32 KB
    __shared__ float lred[64][8];
    __shared__ float invl[64];

    // staging: lane's swizzled source granule (elems); involution i^(i>>3)
    const int gsw = (lane ^ (lane >> 3)) * 8;
    // reading: swizzled byte offset within a 1KB tile for this lane's fragment
    const int tg = l15 * 4 + g;
    const int roff = (tg ^ (tg >> 3)) * 16;

    const unsigned short* krb = tb + (size_t)(b * 32 + w) * RBS + gsw;  // +nb*8*RBS

    f32x4 acc[4][4];   // [nb][mt]
#pragma unroll
    for (int nb = 0; nb < 4; ++nb)
#pragma unroll
        for (int mt = 0; mt < 4; ++mt) acc[nb][mt] = (f32x4){0.f, 0.f, 0.f, 0.f};

#define STAGE(bufi, ds_) {                                                        \
    _Pragma("unroll") for (int nb = 0; nb < 4; ++nb)                              \
        GLDS(krb + (size_t)(nb * 8) * RBS + (ds_) * 512,                          \
             &K_lds[bufi][(nb * 8 + w) * 512]);                                   \
}
#define COMPUTE(bufi) {                                                           \
    const char* Kc = (const char*)K_lds[bufi];                                    \
    short8 qf[4], kf[4];                                                          \
    _Pragma("unroll") for (int mt = 0; mt < 4; ++mt)                              \
        qf[mt] = *(const short8*)(Kc + (qt4 + mt) * 1024 + roff);                 \
    _Pragma("unroll") for (int nb = 0; nb < 4; ++nb)                              \
        kf[nb] = *(const short8*)(Kc + ((nb << 3) + w) * 1024 + roff);            \
    _Pragma("unroll") for (int nb = 0; nb < 4; ++nb)                              \
        _Pragma("unroll") for (int mt = 0; mt < 4; ++mt)                          \
            acc[nb][mt] = __builtin_amdgcn_mfma_f32_16x16x32_bf16(                \
                qf[mt], kf[nb], acc[nb][mt], 0, 0, 0);                            \
}

    // prologue: stages 0 and 1 in flight (8 outstanding loads/wave)
    STAGE(0, 0);
    STAGE(1, 1);

    for (int ds = 0; ds < 30; ++ds) {
        asm volatile("s_waitcnt vmcnt(4)" ::: "memory");   // my stage-ds loads landed
        __builtin_amdgcn_s_barrier();                      // everyone's landed
        __builtin_amdgcn_sched_barrier(0);
        COMPUTE(ds & 1);                                   // ds_reads + MFMAs
        asm volatile("s_waitcnt lgkmcnt(0)" ::: "memory"); // my LDS reads complete
        __builtin_amdgcn_sched_barrier(0);                 // rule-18 fence
        __builtin_amdgcn_s_barrier();                      // everyone done reading buf
        __builtin_amdgcn_sched_barrier(0);
        STAGE(ds & 1, ds + 2);                             // refill; 8 outstanding
    }
    // ds = 30: outstanding = S30(4)+S31(4); no refill
    asm volatile("s_waitcnt vmcnt(4)" ::: "memory");
    __builtin_amdgcn_s_barrier();
    __builtin_amdgcn_sched_barrier(0);
    COMPUTE(0);
    // ds = 31: outstanding = S31(4)
    asm volatile("s_waitcnt vmcnt(0)" ::: "memory");
    __builtin_amdgcn_s_barrier();
    __builtin_amdgcn_sched_barrier(0);
    COMPUTE(1);
#undef STAGE
#undef COMPUTE

    // exp (scale 1/32); q = mt*16 + g*4 + r, k = nb*128 + w*16 + l15
#pragma unroll
    for (int nb = 0; nb < 4; ++nb)
#pragma unroll
        for (int mt = 0; mt < 4; ++mt) {
            f32x4 t = acc[nb][mt];
#pragma unroll
            for (int r = 0; r < 4; ++r) t[r] = __expf(t[r] * 0.03125f);
            acc[nb][mt] = t;
        }

    // row sums: per-thread over nb, then over the 16-lane l15 group
    float rp[4][4];
#pragma unroll
    for (int mt = 0; mt < 4; ++mt)
#pragma unroll
        for (int r = 0; r < 4; ++r) {
            float s = 0.f;
#pragma unroll
            for (int nb = 0; nb < 4; ++nb) s += acc[nb][mt][r];
            rp[mt][r] = s;
        }
#pragma unroll
    for (int m = 1; m <= 8; m <<= 1)
#pragma unroll
        for (int mt = 0; mt < 4; ++mt)
#pragma unroll
            for (int r = 0; r < 4; ++r)
                rp[mt][r] += __shfl_xor(rp[mt][r], m, 64);
    if (l15 == 0) {
#pragma unroll
        for (int mt = 0; mt < 4; ++mt)
#pragma unroll
            for (int r = 0; r < 4; ++r)
                lred[mt * 16 + g * 4 + r][w] = rp[mt][r];
    }
    __syncthreads();
    if (tid < 64) {
        float l = 0.f;
#pragma unroll
        for (int ww = 0; ww < 8; ++ww) l += lred[tid][ww];
        invl[tid] = 1.0f / l;
    }
    __syncthreads();

    float iq[4][4];
#pragma unroll
    for (int mt = 0; mt < 4; ++mt)
#pragma unroll
        for (int r = 0; r < 4; ++r)
            iq[mt][r] = invl[mt * 16 + g * 4 + r];

    // weighted column sums over this block's 64 q rows
#pragma unroll
    for (int nb = 0; nb < 4; ++nb) {
        float cp = 0.f;
#pragma unroll
        for (int mt = 0; mt < 4; ++mt)
#pragma unroll
            for (int r = 0; r < 4; ++r) cp += acc[nb][mt][r] * iq[mt][r];
        cp += __shfl_xor(cp, 16, 64);
        cp += __shfl_xor(cp, 32, 64);
        if (lane < 16)
            c_part[(size_t)blk * 512 + nb * 128 + w * 16 + lane] = cp;
    }
}

// K2: pooled_part from the bf16 tiled buffer.
__global__ __launch_bounds__(256) void k2_pool(const unsigned short* __restrict__ tb,
                                               const float* __restrict__ c_part,
                                               float* __restrict__ pooled_part) {
    const int blk = blockIdx.x;          // 256 = 64 batches * 4 key-ranges
    const int b = blk >> 2, kt = blk & 3;
    const int tid = threadIdx.x;
    __shared__ float cw[128];
    if (tid < 128) {
        int k = kt * 128 + tid;
        float s = 0.f;
#pragma unroll
        for (int qt = 0; qt < 8; ++qt) s += c_part[(size_t)(qt * 64 + b) * 512 + k];
        cw[tid] = s;
    }
    __syncthreads();
    const int cb = tid >> 3;              // d/32
    const int cc = (tid & 7) * 4;         // d%32
    float a0 = 0.f, a1 = 0.f, a2 = 0.f, a3 = 0.f;
    const unsigned short* base = tb + (size_t)(b * 32 + kt * 8) * RBS + cb * 512 + cc;
    for (int kk = 0; kk < 128; ++kk) {
        float c = cw[kk];
        const unsigned short* p = base + (size_t)(kk >> 4) * RBS + (kk & 15) * 32;
        uint2 u = *(const uint2*)p;
        a0 += c * __builtin_bit_cast(float, u.x << 16);
        a1 += c * __builtin_bit_cast(float, u.x & 0xFFFF0000u);
        a2 += c * __builtin_bit_cast(float, u.y << 16);
        a3 += c * __builtin_bit_cast(float, u.y & 0xFFFF0000u);
    }
    float* dst = pooled_part + (size_t)(b * 4 + kt) * DIM + tid * 4;
    *(float4*)dst = make_float4(a0, a1, a2, a3);
}

// K3: out = pooled @ W + bias for both heads. out: [mean(64x512), log_var(64x512)]
__global__ __launch_bounds__(256) void k3_out(const float* __restrict__ pooled_part,
                                              const float* __restrict__ Wm,
                                              const float* __restrict__ bm,
                                              const float* __restrict__ Wv,
                                              const float* __restrict__ bv,
                                              float* __restrict__ out) {
    const int blk = blockIdx.x;          // 128 = 64 batches * 2 heads
    const int b = blk >> 1, which = blk & 1;
    const int tid = threadIdx.x;
    const float* W = which ? Wv : Wm;
    const float* bias = which ? bv : bm;
    __shared__ float p[1024];
#pragma unroll
    for (int i = 0; i < 4; ++i) {
        int d = tid + (i << 8);
        float s = 0.f;
#pragma unroll
        for (int kt = 0; kt < 4; ++kt) s += pooled_part[(size_t)(b * 4 + kt) * DIM + d];
        p[d] = s;
    }
    __syncthreads();
    float acc0 = bias[tid], acc1 = bias[tid + 256];
    for (int d = 0; d < 1024; ++d) {
        float pv = p[d];
        const float* wr = W + (size_t)d * LAT;
        acc0 += pv * wr[tid];
        acc1 += pv * wr[tid + 256];
    }
    float* o = out + (size_t)which * TB * LAT + (size_t)b * LAT;
    o[tid] = acc0;
    o[tid + 256] = acc1;
}

// ============================ fallback path (round-3) =======================
__device__ inline short8 ldfrag_f(const char* lds, int row, int kk, int g) {
    int byte = (row * 256 + kk * 64 + (g << 4)) ^ ((row & 7) << 4);
    return *(const short8*)(lds + byte);
}
__device__ inline void stage_load_f(const float* src, float4* gg) {
    gg[0] = *(const float4*)(src);
    gg[1] = *(const float4*)(src + 4);
    gg[2] = *(const float4*)(src + 8);
    gg[3] = *(const float4*)(src + 12);
}
__device__ inline void stage_write_f(char* lds, int t, const float4* gg) {
    int r = t >> 3;
    int x0 = (t & 7) * 32;
    int sw = (r & 7) << 4;
    uint4v w0, w1;
    w0[0] = pk2(gg[0].x, gg[0].y); w0[1] = pk2(gg[0].z, gg[0].w);
    w0[2] = pk2(gg[1].x, gg[1].y); w0[3] = pk2(gg[1].z, gg[1].w);
    w1[0] = pk2(gg[2].x, gg[2].y); w1[1] = pk2(gg[2].z, gg[2].w);
    w1[2] = pk2(gg[3].x, gg[3].y); w1[3] = pk2(gg[3].z, gg[3].w);
    *(uint4v*)(lds + ((r * 256 + x0) ^ sw))      = w0;
    *(uint4v*)(lds + ((r * 256 + x0 + 16) ^ sw)) = w1;
}
__global__ __launch_bounds__(512, 2) void k1_scores_fb(const float* __restrict__ seq,
                                                       float* __restrict__ c_part) {
    const int blk = blockIdx.x;
    const int b = blk & 63, qt = blk >> 6;
    const int tid = threadIdx.x;
    const int wave = tid >> 6, lane = tid & 63;
    const int qh = wave >> 2, kq = wave & 3;
    const int g = lane >> 4, l15 = lane & 15;
    __shared__ __align__(16) char Qb[16384];
    __shared__ __align__(16) char Kb[2][16384];
    __shared__ float lred[64][4];
    __shared__ float invl[64];
    __shared__ float cred[2][512];
    const float* qbase = seq + (size_t)(b * SL + qt * 64) * DIM;
    const float* kbase = seq + (size_t)(b * SL) * DIM;
    const int sr = tid >> 3;
    const int sx = (tid & 7) * 16;
    f32x4 acc[8][2];
#pragma unroll
    for (int nb = 0; nb < 8; ++nb)
#pragma unroll
        for (int mt = 0; mt < 2; ++mt) acc[nb][mt] = (f32x4){0.f, 0.f, 0.f, 0.f};
    {
        float4 gq[4], gk[4];
        stage_load_f(qbase + (size_t)sr * DIM + sx, gq);
        stage_load_f(kbase + (size_t)sr * DIM + sx, gk);
        stage_write_f(Qb, tid, gq);
        stage_write_f(Kb[0], tid, gk);
        __syncthreads();
    }
    for (int ds = 0; ds < 8; ++ds) {
        short8 qf[2][4];
#pragma unroll
        for (int mt = 0; mt < 2; ++mt)
#pragma unroll
            for (int kk = 0; kk < 4; ++kk)
                qf[mt][kk] = ldfrag_f(Qb, qh * 32 + mt * 16 + l15, kk, g);
#pragma unroll
        for (int nb = 0; nb < 8; ++nb) {
            const char* Kc = Kb[nb & 1];
            float4 gk[4], gq[4];
            if (nb < 7) {
                stage_load_f(kbase + (size_t)((nb + 1) * 64 + sr) * DIM + ds * 128 + sx, gk);
            } else if (ds < 7) {
                stage_load_f(kbase + (size_t)sr * DIM + (ds + 1) * 128 + sx, gk);
                stage_load_f(qbase + (size_t)sr * DIM + (ds + 1) * 128 + sx, gq);
            }
            short8 bf[4];
#pragma unroll
            for (int kk = 0; kk < 4; ++kk) bf[kk] = ldfrag_f(Kc, kq * 16 + l15, kk, g);
#pragma unroll
            for (int mt = 0; mt < 2; ++mt)
#pragma unroll
                for (int kk = 0; kk < 4; ++kk)
                    acc[nb][mt] = __builtin_amdgcn_mfma_f32_16x16x32_bf16(
                        qf[mt][kk], bf[kk], acc[nb][mt], 0, 0, 0);
            __syncthreads();
            if (nb < 7) {
                stage_write_f(Kb[(nb + 1) & 1], tid, gk);
            } else if (ds < 7) {
                stage_write_f(Kb[0], tid, gk);
                stage_write_f(Qb, tid, gq);
            }
            __syncthreads();
        }
    }
#pragma unroll
    for (int nb = 0; nb < 8; ++nb)
#pragma unroll
        for (int mt = 0; mt < 2; ++mt) {
            f32x4 t = acc[nb][mt];
#pragma unroll
            for (int r = 0; r < 4; ++r) t[r] = __expf(t[r] * 0.03125f);
            acc[nb][mt] = t;
        }
    float rp[2][4];
#pragma unroll
    for (int mt = 0; mt < 2; ++mt)
#pragma unroll
        for (int r = 0; r < 4; ++r) {
            float s = 0.f;
#pragma unroll
            for (int nb = 0; nb < 8; ++nb) s += acc[nb][mt][r];
            rp[mt][r] = s;
        }
#pragma unroll
    for (int m = 1; m <= 8; m <<= 1)
#pragma unroll
        for (int mt = 0; mt < 2; ++mt)
#pragma unroll
            for (int r = 0; r < 4; ++r)
                rp[mt][r] += __shfl_xor(rp[mt][r], m, 64);
    if (l15 == 0) {
#pragma unroll
        for (int mt = 0; mt < 2; ++mt)
#pragma unroll
            for (int r = 0; r < 4; ++r)
                lred[qh * 32 + mt * 16 + g * 4 + r][kq] = rp[mt][r];
    }
    __syncthreads();
    if (tid < 64) {
        float l = lred[tid][0] + lred[tid][1] + lred[tid][2] + lred[tid][3];
        invl[tid] = 1.0f / l;
    }
    __syncthreads();
    float iq[2][4];
#pragma unroll
    for (int mt = 0; mt < 2; ++mt)
#pragma unroll
        for (int r = 0; r < 2 * 2; ++r)
            iq[mt][r] = invl[qh * 32 + mt * 16 + g * 4 + r];
#pragma unroll
    for (int nb = 0; nb < 8; ++nb) {
        float cp = 0.f;
#pragma unroll
        for (int mt = 0; mt < 2; ++mt)
#pragma unroll
            for (int r = 0; r < 4; ++r) cp += acc[nb][mt][r] * iq[mt][r];
        cp += __shfl_xor(cp, 16, 64);
        cp += __shfl_xor(cp, 32, 64);
        if (lane < 16) cred[qh][nb * 64 + kq * 16 + lane] = cp;
    }
    __syncthreads();
    c_part[(size_t)blk * 512 + tid] = cred[0][tid] + cred[1][tid];
}
__global__ __launch_bounds__(256) void k2_pool_fb(const float* __restrict__ seq,
                                                  const float* __restrict__ c_part,
                                                  float* __restrict__ pooled_part) {
    const int blk = blockIdx.x;
    const int b = blk >> 2, kt = blk & 3;
    const int tid = threadIdx.x;
    __shared__ float cw[128];
    if (tid < 128) {
        int k = kt * 128 + tid;
        float s = 0.f;
#pragma unroll
        for (int qt = 0; qt < 8; ++qt) s += c_part[(size_t)(qt * 64 + b) * 512 + k];
        cw[tid] = s;
    }
    __syncthreads();
    float a0 = 0.f, a1 = 0.f, a2 = 0.f, a3 = 0.f;
    const float* base = seq + ((size_t)b * SL + kt * 128) * DIM + tid * 4;
    for (int kk = 0; kk < 128; ++kk) {
        float c = cw[kk];
        float4 v = *(const float4*)(base + (size_t)kk * DIM);
        a0 += c * v.x; a1 += c * v.y; a2 += c * v.z; a3 += c * v.w;
    }
    float* dst = pooled_part + (size_t)(b * 4 + kt) * DIM + tid * 4;
    *(float4*)dst = make_float4(a0, a1, a2, a3);
}
// ============================================================================

extern "C" void kernel_launch(void* const* d_in, const int* in_sizes, int n_in,
                              void* d_out, int out_size, void* d_ws, size_t ws_size,
                              hipStream_t stream) {
    const float* seq = (const float*)d_in[0];
    const float* Wm  = (const float*)d_in[1];
    const float* bm  = (const float*)d_in[2];
    const float* Wv  = (const float*)d_in[3];
    const float* bv  = (const float*)d_in[4];
    float* out = (float*)d_out;

    const size_t TBELEMS = (size_t)2048 * RBS;               // padded tiled buf
    const size_t need = TBELEMS * 2 + (512 * 512 + 64 * 4 * DIM) * 4;

    if (ws_size >= need) {
        unsigned short* tbuf = (unsigned short*)d_ws;
        float* c_part      = (float*)((char*)d_ws + TBELEMS * 2);
        float* pooled_part = c_part + 512 * 512;
        hipLaunchKernelGGL(k0_convert, dim3(2048), dim3(256), 0, stream, seq, tbuf);
        hipLaunchKernelGGL(k1_scores,  dim3(512),  dim3(512), 0, stream, tbuf, c_part);
        hipLaunchKernelGGL(k2_pool,    dim3(256),  dim3(256), 0, stream, tbuf, c_part, pooled_part);
        hipLaunchKernelGGL(k3_out,     dim3(128),  dim3(256), 0, stream, pooled_part,
                           Wm, bm, Wv, bv, out);
    } else {
        float* c_part      = (float*)d_ws;
        float* pooled_part = c_part + 512 * 512;
        hipLaunchKernelGGL(k1_scores_fb, dim3(512), dim3(512), 0, stream, seq, c_part);
        hipLaunchKernelGGL(k2_pool_fb,   dim3(256), dim3(256), 0, stream, seq, c_part, pooled_part);
        hipLaunchKernelGGL(k3_out,       dim3(128), dim3(256), 0, stream, pooled_part,
                           Wm, bm, Wv, bv, out);
    }
}

// Round 10
// 104.287 us; speedup vs baseline: 1.5009x; 1.2609x over previous
//
#include <hip/hip_runtime.h>
#include <hip/hip_bf16.h>

#define TB 64     // batches
#define SL 512    // MAX_LEN (all sequences full length)
#define DIM 1024  // feature dim
#define LAT 512   // latent dim

// Tiled bf16 row-block stride in ELEMENTS (16 rows x 1024 cols = 16384 + 256 pad).
#define RBS 16640

typedef short short8 __attribute__((ext_vector_type(8)));
typedef unsigned uint4v __attribute__((ext_vector_type(4)));
typedef float f32x4 __attribute__((ext_vector_type(4)));

__device__ inline unsigned bfr(float f) {   // fp32 -> bf16 bits (RNE), low 16
    unsigned u = __builtin_bit_cast(unsigned, f);
    u += 0x7FFFu + ((u >> 16) & 1u);
    return u >> 16;
}
__device__ inline unsigned pk2(float lo, float hi) {   // pack 2 bf16 into u32
    return bfr(lo) | (bfr(hi) << 16);
}

// ============================================================================
// Tiled bf16 layout: T[rb][cb][16][32], rb = row/16 (2048), cb = col/32 (32).
// One 16x32 tile (1KB) == one MFMA A/B fragment. addr = rb*RBS + cb*512 + r*32+c
// ============================================================================

// K0: fp32 row-major -> bf16 tiled. Block g handles rows g*16..g*16+15.
__global__ __launch_bounds__(256) void k0_convert(const float* __restrict__ seq,
                                                  unsigned short* __restrict__ tb) {
    const int gblk = blockIdx.x;          // 2048 row-groups
    const int tid = threadIdx.x;
    const float* src = seq + (size_t)gblk * 16 * DIM;
    unsigned short* dst = tb + (size_t)gblk * RBS;
    const int cb = tid >> 3;              // tile column 0..31
    const int cc = (tid & 7) * 4;         // col within tile
#pragma unroll
    for (int j = 0; j < 16; ++j) {
        float4 v = *(const float4*)(src + (size_t)j * DIM + tid * 4);
        unsigned short* d = dst + cb * 512 + j * 32 + cc;
        uint2 w;
        w.x = pk2(v.x, v.y);
        w.y = pk2(v.z, v.w);
        *(uint2*)d = w;
    }
}

// Async 1KB tile copy: per-lane global src (16B granules), wave-uniform LDS dst.
#define GLDS(srcp, dstp)                                                          \
    __builtin_amdgcn_global_load_lds(                                             \
        (const __attribute__((address_space(1))) void*)(srcp),                    \
        (__attribute__((address_space(3))) void*)(dstp), 16, 0, 0)

// K1 v6: per-(batch, 64-q-row tile) block, 512 threads (8 waves).
// 2-buffer rotation with counted vmcnt (never 0 in the loop) and RAW
// s_barriers. Iteration: vmcnt(4) | bar | COMPUTE | lgkmcnt(0) | bar | STAGE.
// LDS = 2x32KB + 2.3KB -> 2 blocks/CU (4 waves/SIMD).
__global__ __launch_bounds__(512, 4) void k1_scores(const unsigned short* __restrict__ tb,
                                                    float* __restrict__ c_part) {
    const int blk = blockIdx.x;            // 512 = 8 q-tiles * 64 batches
    const int b = blk & 63, qt = blk >> 6; // same-batch tiles co-XCD
    const int tid = threadIdx.x;
    const int w = tid >> 6, lane = tid & 63;
    const int g = lane >> 4, l15 = lane & 15;
    const int qt4 = qt * 4;

    __shared__ __align__(16) unsigned short K_lds[2][32 * 512];  // 2 x 32 KB
    __shared__ float lred[64][8];
    __shared__ float invl[64];

    // staging: lane's swizzled source granule (elems); involution i^(i>>3)
    const int gsw = (lane ^ (lane >> 3)) * 8;
    // reading: swizzled byte offset within a 1KB tile for this lane's fragment
    const int tg = l15 * 4 + g;
    const int roff = (tg ^ (tg >> 3)) * 16;

    const unsigned short* krb = tb + (size_t)(b * 32 + w) * RBS + gsw;  // +nb*8*RBS

    f32x4 acc[4][4];   // [nb][mt]
#pragma unroll
    for (int nb = 0; nb < 4; ++nb)
#pragma unroll
        for (int mt = 0; mt < 4; ++mt) acc[nb][mt] = (f32x4){0.f, 0.f, 0.f, 0.f};

#define STAGE(bufi, ds_) {                                                        \
    _Pragma("unroll") for (int nb = 0; nb < 4; ++nb)                              \
        GLDS(krb + (size_t)(nb * 8) * RBS + (ds_) * 512,                          \
             &K_lds[bufi][(nb * 8 + w) * 512]);                                   \
}
#define COMPUTE(bufi) {                                                           \
    const char* Kc = (const char*)K_lds[bufi];                                    \
    short8 qf[4], kf[4];                                                          \
    _Pragma("unroll") for (int mt = 0; mt < 4; ++mt)                              \
        qf[mt] = *(const short8*)(Kc + (qt4 + mt) * 1024 + roff);                 \
    _Pragma("unroll") for (int nb = 0; nb < 4; ++nb)                              \
        kf[nb] = *(const short8*)(Kc + ((nb << 3) + w) * 1024 + roff);            \
    _Pragma("unroll") for (int nb = 0; nb < 4; ++nb)                              \
        _Pragma("unroll") for (int mt = 0; mt < 4; ++mt)                          \
            acc[nb][mt] = __builtin_amdgcn_mfma_f32_16x16x32_bf16(                \
                qf[mt], kf[nb], acc[nb][mt], 0, 0, 0);                            \
}

    // prologue: stages 0 and 1 in flight (8 outstanding loads/wave)
    STAGE(0, 0);
    STAGE(1, 1);

    for (int ds = 0; ds < 30; ++ds) {
        asm volatile("s_waitcnt vmcnt(4)" ::: "memory");   // my stage-ds loads landed
        __builtin_amdgcn_s_barrier();                      // everyone's landed
        __builtin_amdgcn_sched_barrier(0);
        COMPUTE(ds & 1);                                   // ds_reads + MFMAs
        asm volatile("s_waitcnt lgkmcnt(0)" ::: "memory"); // my LDS reads complete
        __builtin_amdgcn_sched_barrier(0);                 // rule-18 fence
        __builtin_amdgcn_s_barrier();                      // everyone done reading buf
        __builtin_amdgcn_sched_barrier(0);
        STAGE(ds & 1, ds + 2);                             // refill; 8 outstanding
    }
    // ds = 30: outstanding = S30(4)+S31(4); no refill
    asm volatile("s_waitcnt vmcnt(4)" ::: "memory");
    __builtin_amdgcn_s_barrier();
    __builtin_amdgcn_sched_barrier(0);
    COMPUTE(0);
    // ds = 31: outstanding = S31(4)
    asm volatile("s_waitcnt vmcnt(0)" ::: "memory");
    __builtin_amdgcn_s_barrier();
    __builtin_amdgcn_sched_barrier(0);
    COMPUTE(1);
#undef STAGE
#undef COMPUTE

    // exp (scale 1/32); q = mt*16 + g*4 + r, k = nb*128 + w*16 + l15
#pragma unroll
    for (int nb = 0; nb < 4; ++nb)
#pragma unroll
        for (int mt = 0; mt < 4; ++mt) {
            f32x4 t = acc[nb][mt];
#pragma unroll
            for (int r = 0; r < 4; ++r) t[r] = __expf(t[r] * 0.03125f);
            acc[nb][mt] = t;
        }

    // row sums: per-thread over nb, then over the 16-lane l15 group
    float rp[4][4];
#pragma unroll
    for (int mt = 0; mt < 4; ++mt)
#pragma unroll
        for (int r = 0; r < 4; ++r) {
            float s = 0.f;
#pragma unroll
            for (int nb = 0; nb < 4; ++nb) s += acc[nb][mt][r];
            rp[mt][r] = s;
        }
#pragma unroll
    for (int m = 1; m <= 8; m <<= 1)
#pragma unroll
        for (int mt = 0; mt < 4; ++mt)
#pragma unroll
            for (int r = 0; r < 4; ++r)
                rp[mt][r] += __shfl_xor(rp[mt][r], m, 64);
    if (l15 == 0) {
#pragma unroll
        for (int mt = 0; mt < 4; ++mt)
#pragma unroll
            for (int r = 0; r < 4; ++r)
                lred[mt * 16 + g * 4 + r][w] = rp[mt][r];
    }
    __syncthreads();
    if (tid < 64) {
        float l = 0.f;
#pragma unroll
        for (int ww = 0; ww < 8; ++ww) l += lred[tid][ww];
        invl[tid] = 1.0f / l;
    }
    __syncthreads();

    float iq[4][4];
#pragma unroll
    for (int mt = 0; mt < 4; ++mt)
#pragma unroll
        for (int r = 0; r < 4; ++r)
            iq[mt][r] = invl[mt * 16 + g * 4 + r];

    // weighted column sums over this block's 64 q rows
#pragma unroll
    for (int nb = 0; nb < 4; ++nb) {
        float cp = 0.f;
#pragma unroll
        for (int mt = 0; mt < 4; ++mt)
#pragma unroll
            for (int r = 0; r < 4; ++r) cp += acc[nb][mt][r] * iq[mt][r];
        cp += __shfl_xor(cp, 16, 64);
        cp += __shfl_xor(cp, 32, 64);
        if (lane < 16)
            c_part[(size_t)blk * 512 + nb * 128 + w * 16 + lane] = cp;
    }
}

// K2: pooled_part from the bf16 tiled buffer.
__global__ __launch_bounds__(256) void k2_pool(const unsigned short* __restrict__ tb,
                                               const float* __restrict__ c_part,
                                               float* __restrict__ pooled_part) {
    const int blk = blockIdx.x;          // 256 = 64 batches * 4 key-ranges
    const int b = blk >> 2, kt = blk & 3;
    const int tid = threadIdx.x;
    __shared__ float cw[128];
    if (tid < 128) {
        int k = kt * 128 + tid;
        float s = 0.f;
#pragma unroll
        for (int qt = 0; qt < 8; ++qt) s += c_part[(size_t)(qt * 64 + b) * 512 + k];
        cw[tid] = s;
    }
    __syncthreads();
    const int cb = tid >> 3;              // d/32
    const int cc = (tid & 7) * 4;         // d%32
    float a0 = 0.f, a1 = 0.f, a2 = 0.f, a3 = 0.f;
    const unsigned short* base = tb + (size_t)(b * 32 + kt * 8) * RBS + cb * 512 + cc;
    for (int kk = 0; kk < 128; ++kk) {
        float c = cw[kk];
        const unsigned short* p = base + (size_t)(kk >> 4) * RBS + (kk & 15) * 32;
        uint2 u = *(const uint2*)p;
        a0 += c * __builtin_bit_cast(float, u.x << 16);
        a1 += c * __builtin_bit_cast(float, u.x & 0xFFFF0000u);
        a2 += c * __builtin_bit_cast(float, u.y << 16);
        a3 += c * __builtin_bit_cast(float, u.y & 0xFFFF0000u);
    }
    float* dst = pooled_part + (size_t)(b * 4 + kt) * DIM + tid * 4;
    *(float4*)dst = make_float4(a0, a1, a2, a3);
}

// K3a: partial GEMM. Grid 256 = h(2) x kq(4) x bg(32); each block: 2 batches,
// d-quarter kq (256 of 1024), all 512 latent cols. part[h][kq][b][l].
#define BG 2
__global__ __launch_bounds__(256) void k3a_gemm(const float* __restrict__ pooled_part,
                                                const float* __restrict__ Wm,
                                                const float* __restrict__ Wv,
                                                float* __restrict__ part) {
    const int blk = blockIdx.x;
    const int h  = blk >> 7;             // head
    const int kq = (blk >> 5) & 3;       // d-quarter
    const int bg = blk & 31;             // batch group (BG=2)
    const int tid = threadIdx.x;
    const float* W = h ? Wv : Wm;
    __shared__ float p[BG][256];
#pragma unroll
    for (int j = 0; j < BG; ++j) {
        float s = 0.f;
#pragma unroll
        for (int kt = 0; kt < 4; ++kt)
            s += pooled_part[(size_t)((bg * BG + j) * 4 + kt) * DIM + kq * 256 + tid];
        p[j][tid] = s;
    }
    __syncthreads();
    float a00 = 0.f, a01 = 0.f, a10 = 0.f, a11 = 0.f;
    const float* wbase = W + (size_t)(kq * 256) * LAT;
#pragma unroll 4
    for (int d = 0; d < 256; ++d) {
        float w0 = wbase[(size_t)d * LAT + tid];
        float w1 = wbase[(size_t)d * LAT + tid + 256];
        float p0 = p[0][d], p1 = p[1][d];
        a00 += p0 * w0; a01 += p0 * w1;
        a10 += p1 * w0; a11 += p1 * w1;
    }
    {
        int b = bg * BG;
        float* dst = part + (size_t)(((h * 4 + kq) * 64) + b) * 512;
        dst[tid] = a00; dst[tid + 256] = a01;
        dst[512 + tid] = a10; dst[512 + tid + 256] = a11;
    }
}

// K3b: out[h][b][l] = bias_h[l] + sum_kq part[h][kq][b][l]
__global__ __launch_bounds__(256) void k3b_reduce(const float* __restrict__ part,
                                                  const float* __restrict__ bm,
                                                  const float* __restrict__ bv,
                                                  float* __restrict__ out) {
    const int blk = blockIdx.x;          // 128 = h*64 + b
    const int h = blk >> 6, b = blk & 63;
    const int tid = threadIdx.x;
    const float* bias = h ? bv : bm;
#pragma unroll
    for (int i = 0; i < 2; ++i) {
        int l = tid + (i << 8);
        float s = bias[l];
#pragma unroll
        for (int kq = 0; kq < 4; ++kq)
            s += part[(size_t)(((h * 4 + kq) * 64) + b) * 512 + l];
        out[(size_t)h * TB * LAT + (size_t)b * LAT + l] = s;
    }
}

// K3 (fallback only): out = pooled @ W + bias for both heads.
__global__ __launch_bounds__(256) void k3_out(const float* __restrict__ pooled_part,
                                              const float* __restrict__ Wm,
                                              const float* __restrict__ bm,
                                              const float* __restrict__ Wv,
                                              const float* __restrict__ bv,
                                              float* __restrict__ out) {
    const int blk = blockIdx.x;          // 128 = 64 batches * 2 heads
    const int b = blk >> 1, which = blk & 1;
    const int tid = threadIdx.x;
    const float* W = which ? Wv : Wm;
    const float* bias = which ? bv : bm;
    __shared__ float p[1024];
#pragma unroll
    for (int i = 0; i < 4; ++i) {
        int d = tid + (i << 8);
        float s = 0.f;
#pragma unroll
        for (int kt = 0; kt < 4; ++kt) s += pooled_part[(size_t)(b * 4 + kt) * DIM + d];
        p[d] = s;
    }
    __syncthreads();
    float acc0 = bias[tid], acc1 = bias[tid + 256];
    for (int d = 0; d < 1024; ++d) {
        float pv = p[d];
        const float* wr = W + (size_t)d * LAT;
        acc0 += pv * wr[tid];
        acc1 += pv * wr[tid + 256];
    }
    float* o = out + (size_t)which * TB * LAT + (size_t)b * LAT;
    o[tid] = acc0;
    o[tid + 256] = acc1;
}

// ============================ fallback path (round-3) =======================
__device__ inline short8 ldfrag_f(const char* lds, int row, int kk, int g) {
    int byte = (row * 256 + kk * 64 + (g << 4)) ^ ((row & 7) << 4);
    return *(const short8*)(lds + byte);
}
__device__ inline void stage_load_f(const float* src, float4* gg) {
    gg[0] = *(const float4*)(src);
    gg[1] = *(const float4*)(src + 4);
    gg[2] = *(const float4*)(src + 8);
    gg[3] = *(const float4*)(src + 12);
}
__device__ inline void stage_write_f(char* lds, int t, const float4* gg) {
    int r = t >> 3;
    int x0 = (t & 7) * 32;
    int sw = (r & 7) << 4;
    uint4v w0, w1;
    w0[0] = pk2(gg[0].x, gg[0].y); w0[1] = pk2(gg[0].z, gg[0].w);
    w0[2] = pk2(gg[1].x, gg[1].y); w0[3] = pk2(gg[1].z, gg[1].w);
    w1[0] = pk2(gg[2].x, gg[2].y); w1[1] = pk2(gg[2].z, gg[2].w);
    w1[2] = pk2(gg[3].x, gg[3].y); w1[3] = pk2(gg[3].z, gg[3].w);
    *(uint4v*)(lds + ((r * 256 + x0) ^ sw))      = w0;
    *(uint4v*)(lds + ((r * 256 + x0 + 16) ^ sw)) = w1;
}
__global__ __launch_bounds__(512, 2) void k1_scores_fb(const float* __restrict__ seq,
                                                       float* __restrict__ c_part) {
    const int blk = blockIdx.x;
    const int b = blk & 63, qt = blk >> 6;
    const int tid = threadIdx.x;
    const int wave = tid >> 6, lane = tid & 63;
    const int qh = wave >> 2, kq = wave & 3;
    const int g = lane >> 4, l15 = lane & 15;
    __shared__ __align__(16) char Qb[16384];
    __shared__ __align__(16) char Kb[2][16384];
    __shared__ float lred[64][4];
    __shared__ float invl[64];
    __shared__ float cred[2][512];
    const float* qbase = seq + (size_t)(b * SL + qt * 64) * DIM;
    const float* kbase = seq + (size_t)(b * SL) * DIM;
    const int sr = tid >> 3;
    const int sx = (tid & 7) * 16;
    f32x4 acc[8][2];
#pragma unroll
    for (int nb = 0; nb < 8; ++nb)
#pragma unroll
        for (int mt = 0; mt < 2; ++mt) acc[nb][mt] = (f32x4){0.f, 0.f, 0.f, 0.f};
    {
        float4 gq[4], gk[4];
        stage_load_f(qbase + (size_t)sr * DIM + sx, gq);
        stage_load_f(kbase + (size_t)sr * DIM + sx, gk);
        stage_write_f(Qb, tid, gq);
        stage_write_f(Kb[0], tid, gk);
        __syncthreads();
    }
    for (int ds = 0; ds < 8; ++ds) {
        short8 qf[2][4];
#pragma unroll
        for (int mt = 0; mt < 2; ++mt)
#pragma unroll
            for (int kk = 0; kk < 4; ++kk)
                qf[mt][kk] = ldfrag_f(Qb, qh * 32 + mt * 16 + l15, kk, g);
#pragma unroll
        for (int nb = 0; nb < 8; ++nb) {
            const char* Kc = Kb[nb & 1];
            float4 gk[4], gq[4];
            if (nb < 7) {
                stage_load_f(kbase + (size_t)((nb + 1) * 64 + sr) * DIM + ds * 128 + sx, gk);
            } else if (ds < 7) {
                stage_load_f(kbase + (size_t)sr * DIM + (ds + 1) * 128 + sx, gk);
                stage_load_f(qbase + (size_t)sr * DIM + (ds + 1) * 128 + sx, gq);
            }
            short8 bf[4];
#pragma unroll
            for (int kk = 0; kk < 4; ++kk) bf[kk] = ldfrag_f(Kc, kq * 16 + l15, kk, g);
#pragma unroll
            for (int mt = 0; mt < 2; ++mt)
#pragma unroll
                for (int kk = 0; kk < 4; ++kk)
                    acc[nb][mt] = __builtin_amdgcn_mfma_f32_16x16x32_bf16(
                        qf[mt][kk], bf[kk], acc[nb][mt], 0, 0, 0);
            __syncthreads();
            if (nb < 7) {
                stage_write_f(Kb[(nb + 1) & 1], tid, gk);
            } else if (ds < 7) {
                stage_write_f(Kb[0], tid, gk);
                stage_write_f(Qb, tid, gq);
            }
            __syncthreads();
        }
    }
#pragma unroll
    for (int nb = 0; nb < 8; ++nb)
#pragma unroll
        for (int mt = 0; mt < 2; ++mt) {
            f32x4 t = acc[nb][mt];
#pragma unroll
            for (int r = 0; r < 4; ++r) t[r] = __expf(t[r] * 0.03125f);
            acc[nb][mt] = t;
        }
    float rp[2][4];
#pragma unroll
    for (int mt = 0; mt < 2; ++mt)
#pragma unroll
        for (int r = 0; r < 4; ++r) {
            float s = 0.f;
#pragma unroll
            for (int nb = 0; nb < 8; ++nb) s += acc[nb][mt][r];
            rp[mt][r] = s;
        }
#pragma unroll
    for (int m = 1; m <= 8; m <<= 1)
#pragma unroll
        for (int mt = 0; mt < 2; ++mt)
#pragma unroll
            for (int r = 0; r < 4; ++r)
                rp[mt][r] += __shfl_xor(rp[mt][r], m, 64);
    if (l15 == 0) {
#pragma unroll
        for (int mt = 0; mt < 2; ++mt)
#pragma unroll
            for (int r = 0; r < 4; ++r)
                lred[qh * 32 + mt * 16 + g * 4 + r][kq] = rp[mt][r];
    }
    __syncthreads();
    if (tid < 64) {
        float l = lred[tid][0] + lred[tid][1] + lred[tid][2] + lred[tid][3];
        invl[tid] = 1.0f / l;
    }
    __syncthreads();
    float iq[2][4];
#pragma unroll
    for (int mt = 0; mt < 2; ++mt)
#pragma unroll
        for (int r = 0; r < 4; ++r)
            iq[mt][r] = invl[qh * 32 + mt * 16 + g * 4 + r];
#pragma unroll
    for (int nb = 0; nb < 8; ++nb) {
        float cp = 0.f;
#pragma unroll
        for (int mt = 0; mt < 2; ++mt)
#pragma unroll
            for (int r = 0; r < 4; ++r) cp += acc[nb][mt][r] * iq[mt][r];
        cp += __shfl_xor(cp, 16, 64);
        cp += __shfl_xor(cp, 32, 64);
        if (lane < 16) cred[qh][nb * 64 + kq * 16 + lane] = cp;
    }
    __syncthreads();
    c_part[(size_t)blk * 512 + tid] = cred[0][tid] + cred[1][tid];
}
__global__ __launch_bounds__(256) void k2_pool_fb(const float* __restrict__ seq,
                                                  const float* __restrict__ c_part,
                                                  float* __restrict__ pooled_part) {
    const int blk = blockIdx.x;
    const int b = blk >> 2, kt = blk & 3;
    const int tid = threadIdx.x;
    __shared__ float cw[128];
    if (tid < 128) {
        int k = kt * 128 + tid;
        float s = 0.f;
#pragma unroll
        for (int qt = 0; qt < 8; ++qt) s += c_part[(size_t)(qt * 64 + b) * 512 + k];
        cw[tid] = s;
    }
    __syncthreads();
    float a0 = 0.f, a1 = 0.f, a2 = 0.f, a3 = 0.f;
    const float* base = seq + ((size_t)b * SL + kt * 128) * DIM + tid * 4;
    for (int kk = 0; kk < 128; ++kk) {
        float c = cw[kk];
        float4 v = *(const float4*)(base + (size_t)kk * DIM);
        a0 += c * v.x; a1 += c * v.y; a2 += c * v.z; a3 += c * v.w;
    }
    float* dst = pooled_part + (size_t)(b * 4 + kt) * DIM + tid * 4;
    *(float4*)dst = make_float4(a0, a1, a2, a3);
}
// ============================================================================

extern "C" void kernel_launch(void* const* d_in, const int* in_sizes, int n_in,
                              void* d_out, int out_size, void* d_ws, size_t ws_size,
                              hipStream_t stream) {
    const float* seq = (const float*)d_in[0];
    const float* Wm  = (const float*)d_in[1];
    const float* bm  = (const float*)d_in[2];
    const float* Wv  = (const float*)d_in[3];
    const float* bv  = (const float*)d_in[4];
    float* out = (float*)d_out;

    const size_t TBELEMS = (size_t)2048 * RBS;               // padded tiled buf
    const size_t FELEMS  = 512 * 512 + 64 * 4 * DIM + 2 * 4 * 64 * 512;
    const size_t need = TBELEMS * 2 + FELEMS * 4;

    if (ws_size >= need) {
        unsigned short* tbuf = (unsigned short*)d_ws;
        float* c_part      = (float*)((char*)d_ws + TBELEMS * 2);
        float* pooled_part = c_part + 512 * 512;
        float* part        = pooled_part + 64 * 4 * DIM;
        hipLaunchKernelGGL(k0_convert, dim3(2048), dim3(256), 0, stream, seq, tbuf);
        hipLaunchKernelGGL(k1_scores,  dim3(512),  dim3(512), 0, stream, tbuf, c_part);
        hipLaunchKernelGGL(k2_pool,    dim3(256),  dim3(256), 0, stream, tbuf, c_part, pooled_part);
        hipLaunchKernelGGL(k3a_gemm,   dim3(256),  dim3(256), 0, stream, pooled_part,
                           Wm, Wv, part);
        hipLaunchKernelGGL(k3b_reduce, dim3(128),  dim3(256), 0, stream, part,
                           bm, bv, out);
    } else {
        float* c_part      = (float*)d_ws;
        float* pooled_part = c_part + 512 * 512;
        hipLaunchKernelGGL(k1_scores_fb, dim3(512), dim3(512), 0, stream, seq, c_part);
        hipLaunchKernelGGL(k2_pool_fb,   dim3(256), dim3(256), 0, stream, seq, c_part, pooled_part);
        hipLaunchKernelGGL(k3_out,       dim3(128), dim3(256), 0, stream, pooled_part,
                           Wm, bm, Wv, bv, out);
    }
}

// Round 11
// 95.168 us; speedup vs baseline: 1.6447x; 1.0958x over previous
//
#include <hip/hip_runtime.h>
#include <hip/hip_bf16.h>

#define TB 64     // batches
#define SL 512    // MAX_LEN (all sequences full length)
#define DIM 1024  // feature dim
#define LAT 512   // latent dim

// Tiled bf16 row-block stride in ELEMENTS (16 rows x 1024 cols = 16384 + 256 pad).
#define RBS 16640

typedef short short8 __attribute__((ext_vector_type(8)));
typedef unsigned uint4v __attribute__((ext_vector_type(4)));
typedef float f32x4 __attribute__((ext_vector_type(4)));

__device__ inline unsigned bfr(float f) {   // fp32 -> bf16 bits (RNE), low 16
    unsigned u = __builtin_bit_cast(unsigned, f);
    u += 0x7FFFu + ((u >> 16) & 1u);
    return u >> 16;
}
__device__ inline unsigned pk2(float lo, float hi) {   // pack 2 bf16 into u32
    return bfr(lo) | (bfr(hi) << 16);
}

// ============================================================================
// Tiled bf16 layout: T[rb][cb][16][32], rb = row/16 (2048), cb = col/32 (32).
// One 16x32 tile (1KB) == one MFMA A/B fragment. addr = rb*RBS + cb*512 + r*32+c
// ============================================================================

// K0: fp32 row-major -> bf16 tiled. Block g handles rows g*16..g*16+15.
__global__ __launch_bounds__(256) void k0_convert(const float* __restrict__ seq,
                                                  unsigned short* __restrict__ tb) {
    const int gblk = blockIdx.x;          // 2048 row-groups
    const int tid = threadIdx.x;
    const float* src = seq + (size_t)gblk * 16 * DIM;
    unsigned short* dst = tb + (size_t)gblk * RBS;
    const int cb = tid >> 3;              // tile column 0..31
    const int cc = (tid & 7) * 4;         // col within tile
#pragma unroll
    for (int j = 0; j < 16; ++j) {
        float4 v = *(const float4*)(src + (size_t)j * DIM + tid * 4);
        unsigned short* d = dst + cb * 512 + j * 32 + cc;
        uint2 w;
        w.x = pk2(v.x, v.y);
        w.y = pk2(v.z, v.w);
        *(uint2*)d = w;
    }
}

// Async 1KB tile copy: per-lane global src (16B granules), wave-uniform LDS dst.
#define GLDS(srcp, dstp)                                                          \
    __builtin_amdgcn_global_load_lds(                                             \
        (const __attribute__((address_space(1))) void*)(srcp),                    \
        (__attribute__((address_space(3))) void*)(dstp), 16, 0, 0)

// K1 v6: per-(batch, 64-q-row tile) block, 512 threads (8 waves).
// 2-buffer rotation with counted vmcnt (never 0 in the loop) and RAW
// s_barriers. Iteration: vmcnt(4) | bar | COMPUTE | lgkmcnt(0) | bar | STAGE.
// LDS = 2x32KB + 2.3KB -> 2 blocks/CU (4 waves/SIMD).
__global__ __launch_bounds__(512, 4) void k1_scores(const unsigned short* __restrict__ tb,
                                                    float* __restrict__ c_part) {
    const int blk = blockIdx.x;            // 512 = 8 q-tiles * 64 batches
    const int b = blk & 63, qt = blk >> 6; // same-batch tiles co-XCD
    const int tid = threadIdx.x;
    const int w = tid >> 6, lane = tid & 63;
    const int g = lane >> 4, l15 = lane & 15;
    const int qt4 = qt * 4;

    __shared__ __align__(16) unsigned short K_lds[2][32 * 512];  // 2 x 32 KB
    __shared__ float lred[64][8];
    __shared__ float invl[64];

    // staging: lane's swizzled source granule (elems); involution i^(i>>3)
    const int gsw = (lane ^ (lane >> 3)) * 8;
    // reading: swizzled byte offset within a 1KB tile for this lane's fragment
    const int tg = l15 * 4 + g;
    const int roff = (tg ^ (tg >> 3)) * 16;

    const unsigned short* krb = tb + (size_t)(b * 32 + w) * RBS + gsw;  // +nb*8*RBS

    f32x4 acc[4][4];   // [nb][mt]
#pragma unroll
    for (int nb = 0; nb < 4; ++nb)
#pragma unroll
        for (int mt = 0; mt < 4; ++mt) acc[nb][mt] = (f32x4){0.f, 0.f, 0.f, 0.f};

#define STAGE(bufi, ds_) {                                                        \
    _Pragma("unroll") for (int nb = 0; nb < 4; ++nb)                              \
        GLDS(krb + (size_t)(nb * 8) * RBS + (ds_) * 512,                          \
             &K_lds[bufi][(nb * 8 + w) * 512]);                                   \
}
#define COMPUTE(bufi) {                                                           \
    const char* Kc = (const char*)K_lds[bufi];                                    \
    short8 qf[4], kf[4];                                                          \
    _Pragma("unroll") for (int mt = 0; mt < 4; ++mt)                              \
        qf[mt] = *(const short8*)(Kc + (qt4 + mt) * 1024 + roff);                 \
    _Pragma("unroll") for (int nb = 0; nb < 4; ++nb)                              \
        kf[nb] = *(const short8*)(Kc + ((nb << 3) + w) * 1024 + roff);            \
    _Pragma("unroll") for (int nb = 0; nb < 4; ++nb)                              \
        _Pragma("unroll") for (int mt = 0; mt < 4; ++mt)                          \
            acc[nb][mt] = __builtin_amdgcn_mfma_f32_16x16x32_bf16(                \
                qf[mt], kf[nb], acc[nb][mt], 0, 0, 0);                            \
}

    // prologue: stages 0 and 1 in flight (8 outstanding loads/wave)
    STAGE(0, 0);
    STAGE(1, 1);

    for (int ds = 0; ds < 30; ++ds) {
        asm volatile("s_waitcnt vmcnt(4)" ::: "memory");   // my stage-ds loads landed
        __builtin_amdgcn_s_barrier();                      // everyone's landed
        __builtin_amdgcn_sched_barrier(0);
        COMPUTE(ds & 1);                                   // ds_reads + MFMAs
        asm volatile("s_waitcnt lgkmcnt(0)" ::: "memory"); // my LDS reads complete
        __builtin_amdgcn_sched_barrier(0);                 // rule-18 fence
        __builtin_amdgcn_s_barrier();                      // everyone done reading buf
        __builtin_amdgcn_sched_barrier(0);
        STAGE(ds & 1, ds + 2);                             // refill; 8 outstanding
    }
    // ds = 30: outstanding = S30(4)+S31(4); no refill
    asm volatile("s_waitcnt vmcnt(4)" ::: "memory");
    __builtin_amdgcn_s_barrier();
    __builtin_amdgcn_sched_barrier(0);
    COMPUTE(0);
    // ds = 31: outstanding = S31(4)
    asm volatile("s_waitcnt vmcnt(0)" ::: "memory");
    __builtin_amdgcn_s_barrier();
    __builtin_amdgcn_sched_barrier(0);
    COMPUTE(1);
#undef STAGE
#undef COMPUTE

    // exp (scale 1/32); q = mt*16 + g*4 + r, k = nb*128 + w*16 + l15
#pragma unroll
    for (int nb = 0; nb < 4; ++nb)
#pragma unroll
        for (int mt = 0; mt < 4; ++mt) {
            f32x4 t = acc[nb][mt];
#pragma unroll
            for (int r = 0; r < 4; ++r) t[r] = __expf(t[r] * 0.03125f);
            acc[nb][mt] = t;
        }

    // row sums: per-thread over nb, then over the 16-lane l15 group
    float rp[4][4];
#pragma unroll
    for (int mt = 0; mt < 4; ++mt)
#pragma unroll
        for (int r = 0; r < 4; ++r) {
            float s = 0.f;
#pragma unroll
            for (int nb = 0; nb < 4; ++nb) s += acc[nb][mt][r];
            rp[mt][r] = s;
        }
#pragma unroll
    for (int m = 1; m <= 8; m <<= 1)
#pragma unroll
        for (int mt = 0; mt < 4; ++mt)
#pragma unroll
            for (int r = 0; r < 4; ++r)
                rp[mt][r] += __shfl_xor(rp[mt][r], m, 64);
    if (l15 == 0) {
#pragma unroll
        for (int mt = 0; mt < 4; ++mt)
#pragma unroll
            for (int r = 0; r < 4; ++r)
                lred[mt * 16 + g * 4 + r][w] = rp[mt][r];
    }
    __syncthreads();
    if (tid < 64) {
        float l = 0.f;
#pragma unroll
        for (int ww = 0; ww < 8; ++ww) l += lred[tid][ww];
        invl[tid] = 1.0f / l;
    }
    __syncthreads();

    float iq[4][4];
#pragma unroll
    for (int mt = 0; mt < 4; ++mt)
#pragma unroll
        for (int r = 0; r < 4; ++r)
            iq[mt][r] = invl[mt * 16 + g * 4 + r];

    // weighted column sums over this block's 64 q rows
#pragma unroll
    for (int nb = 0; nb < 4; ++nb) {
        float cp = 0.f;
#pragma unroll
        for (int mt = 0; mt < 4; ++mt)
#pragma unroll
            for (int r = 0; r < 4; ++r) cp += acc[nb][mt][r] * iq[mt][r];
        cp += __shfl_xor(cp, 16, 64);
        cp += __shfl_xor(cp, 32, 64);
        if (lane < 16)
            c_part[(size_t)blk * 512 + nb * 128 + w * 16 + lane] = cp;
    }
}

// K2: pooled_part from the bf16 tiled buffer.
__global__ __launch_bounds__(256) void k2_pool(const unsigned short* __restrict__ tb,
                                               const float* __restrict__ c_part,
                                               float* __restrict__ pooled_part) {
    const int blk = blockIdx.x;          // 256 = 64 batches * 4 key-ranges
    const int b = blk >> 2, kt = blk & 3;
    const int tid = threadIdx.x;
    __shared__ float cw[128];
    if (tid < 128) {
        int k = kt * 128 + tid;
        float s = 0.f;
#pragma unroll
        for (int qt = 0; qt < 8; ++qt) s += c_part[(size_t)(qt * 64 + b) * 512 + k];
        cw[tid] = s;
    }
    __syncthreads();
    const int cb = tid >> 3;              // d/32
    const int cc = (tid & 7) * 4;         // d%32
    float a0 = 0.f, a1 = 0.f, a2 = 0.f, a3 = 0.f;
    const unsigned short* base = tb + (size_t)(b * 32 + kt * 8) * RBS + cb * 512 + cc;
    for (int kk = 0; kk < 128; ++kk) {
        float c = cw[kk];
        const unsigned short* p = base + (size_t)(kk >> 4) * RBS + (kk & 15) * 32;
        uint2 u = *(const uint2*)p;
        a0 += c * __builtin_bit_cast(float, u.x << 16);
        a1 += c * __builtin_bit_cast(float, u.x & 0xFFFF0000u);
        a2 += c * __builtin_bit_cast(float, u.y << 16);
        a3 += c * __builtin_bit_cast(float, u.y & 0xFFFF0000u);
    }
    float* dst = pooled_part + (size_t)(b * 4 + kt) * DIM + tid * 4;
    *(float4*)dst = make_float4(a0, a1, a2, a3);
}

// K3a v2: partial GEMM, grid 2048 = b(64) x 32 W-slices.
// Slice s = h*16 + dq*2 + lh lives in blk's LOW 5 bits -> all 64 blocks
// sharing a W slice have blk%8 == s%8 -> SAME XCD -> W fetched once/slice.
// 8 blocks/CU co-resident -> full TLP (vs 1 wave/SIMD in v1).
__global__ __launch_bounds__(256) void k3a_gemm(const float* __restrict__ pooled_part,
                                                const float* __restrict__ Wm,
                                                const float* __restrict__ Wv,
                                                float* __restrict__ part) {
    const int blk = blockIdx.x;          // 2048
    const int s  = blk & 31;             // W-slice id (XCD-aligned)
    const int b  = blk >> 5;             // batch
    const int h  = s >> 4;               // head
    const int dq = (s >> 1) & 7;         // d-slice of 128
    const int lh = s & 1;                // latent half of 256
    const int tid = threadIdx.x;
    const float* W = h ? Wv : Wm;
    __shared__ float p[128];
    if (tid < 128) {
        float v = 0.f;
#pragma unroll
        for (int kt = 0; kt < 4; ++kt)
            v += pooled_part[(size_t)(b * 4 + kt) * DIM + dq * 128 + tid];
        p[tid] = v;
    }
    __syncthreads();
    float acc = 0.f;
    const float* wb = W + (size_t)(dq * 128) * LAT + lh * 256 + tid;
#pragma unroll 8
    for (int d = 0; d < 128; ++d)
        acc += p[d] * wb[(size_t)d * LAT];
    part[(size_t)(((h * 8 + dq) * 64) + b) * 512 + lh * 256 + tid] = acc;
}

// K3b: out[h][b][l] = bias_h[l] + sum_dq part[h][dq][b][l]
__global__ __launch_bounds__(256) void k3b_reduce(const float* __restrict__ part,
                                                  const float* __restrict__ bm,
                                                  const float* __restrict__ bv,
                                                  float* __restrict__ out) {
    const int blk = blockIdx.x;          // 128 = h*64 + b
    const int h = blk >> 6, b = blk & 63;
    const int tid = threadIdx.x;
    const float* bias = h ? bv : bm;
#pragma unroll
    for (int i = 0; i < 2; ++i) {
        int l = tid + (i << 8);
        float sv = bias[l];
#pragma unroll
        for (int dq = 0; dq < 8; ++dq)
            sv += part[(size_t)(((h * 8 + dq) * 64) + b) * 512 + l];
        out[(size_t)h * TB * LAT + (size_t)b * LAT + l] = sv;
    }
}

// K3 (fallback only): out = pooled @ W + bias for both heads.
__global__ __launch_bounds__(256) void k3_out(const float* __restrict__ pooled_part,
                                              const float* __restrict__ Wm,
                                              const float* __restrict__ bm,
                                              const float* __restrict__ Wv,
                                              const float* __restrict__ bv,
                                              float* __restrict__ out) {
    const int blk = blockIdx.x;          // 128 = 64 batches * 2 heads
    const int b = blk >> 1, which = blk & 1;
    const int tid = threadIdx.x;
    const float* W = which ? Wv : Wm;
    const float* bias = which ? bv : bm;
    __shared__ float p[1024];
#pragma unroll
    for (int i = 0; i < 4; ++i) {
        int d = tid + (i << 8);
        float s = 0.f;
#pragma unroll
        for (int kt = 0; kt < 4; ++kt) s += pooled_part[(size_t)(b * 4 + kt) * DIM + d];
        p[d] = s;
    }
    __syncthreads();
    float acc0 = bias[tid], acc1 = bias[tid + 256];
    for (int d = 0; d < 1024; ++d) {
        float pv = p[d];
        const float* wr = W + (size_t)d * LAT;
        acc0 += pv * wr[tid];
        acc1 += pv * wr[tid + 256];
    }
    float* o = out + (size_t)which * TB * LAT + (size_t)b * LAT;
    o[tid] = acc0;
    o[tid + 256] = acc1;
}

// ============================ fallback path (round-3) =======================
__device__ inline short8 ldfrag_f(const char* lds, int row, int kk, int g) {
    int byte = (row * 256 + kk * 64 + (g << 4)) ^ ((row & 7) << 4);
    return *(const short8*)(lds + byte);
}
__device__ inline void stage_load_f(const float* src, float4* gg) {
    gg[0] = *(const float4*)(src);
    gg[1] = *(const float4*)(src + 4);
    gg[2] = *(const float4*)(src + 8);
    gg[3] = *(const float4*)(src + 12);
}
__device__ inline void stage_write_f(char* lds, int t, const float4* gg) {
    int r = t >> 3;
    int x0 = (t & 7) * 32;
    int sw = (r & 7) << 4;
    uint4v w0, w1;
    w0[0] = pk2(gg[0].x, gg[0].y); w0[1] = pk2(gg[0].z, gg[0].w);
    w0[2] = pk2(gg[1].x, gg[1].y); w0[3] = pk2(gg[1].z, gg[1].w);
    w1[0] = pk2(gg[2].x, gg[2].y); w1[1] = pk2(gg[2].z, gg[2].w);
    w1[2] = pk2(gg[3].x, gg[3].y); w1[3] = pk2(gg[3].z, gg[3].w);
    *(uint4v*)(lds + ((r * 256 + x0) ^ sw))      = w0;
    *(uint4v*)(lds + ((r * 256 + x0 + 16) ^ sw)) = w1;
}
__global__ __launch_bounds__(512, 2) void k1_scores_fb(const float* __restrict__ seq,
                                                       float* __restrict__ c_part) {
    const int blk = blockIdx.x;
    const int b = blk & 63, qt = blk >> 6;
    const int tid = threadIdx.x;
    const int wave = tid >> 6, lane = tid & 63;
    const int qh = wave >> 2, kq = wave & 3;
    const int g = lane >> 4, l15 = lane & 15;
    __shared__ __align__(16) char Qb[16384];
    __shared__ __align__(16) char Kb[2][16384];
    __shared__ float lred[64][4];
    __shared__ float invl[64];
    __shared__ float cred[2][512];
    const float* qbase = seq + (size_t)(b * SL + qt * 64) * DIM;
    const float* kbase = seq + (size_t)(b * SL) * DIM;
    const int sr = tid >> 3;
    const int sx = (tid & 7) * 16;
    f32x4 acc[8][2];
#pragma unroll
    for (int nb = 0; nb < 8; ++nb)
#pragma unroll
        for (int mt = 0; mt < 2; ++mt) acc[nb][mt] = (f32x4){0.f, 0.f, 0.f, 0.f};
    {
        float4 gq[4], gk[4];
        stage_load_f(qbase + (size_t)sr * DIM + sx, gq);
        stage_load_f(kbase + (size_t)sr * DIM + sx, gk);
        stage_write_f(Qb, tid, gq);
        stage_write_f(Kb[0], tid, gk);
        __syncthreads();
    }
    for (int ds = 0; ds < 8; ++ds) {
        short8 qf[2][4];
#pragma unroll
        for (int mt = 0; mt < 2; ++mt)
#pragma unroll
            for (int kk = 0; kk < 4; ++kk)
                qf[mt][kk] = ldfrag_f(Qb, qh * 32 + mt * 16 + l15, kk, g);
#pragma unroll
        for (int nb = 0; nb < 8; ++nb) {
            const char* Kc = Kb[nb & 1];
            float4 gk[4], gq[4];
            if (nb < 7) {
                stage_load_f(kbase + (size_t)((nb + 1) * 64 + sr) * DIM + ds * 128 + sx, gk);
            } else if (ds < 7) {
                stage_load_f(kbase + (size_t)sr * DIM + (ds + 1) * 128 + sx, gk);
                stage_load_f(qbase + (size_t)sr * DIM + (ds + 1) * 128 + sx, gq);
            }
            short8 bf[4];
#pragma unroll
            for (int kk = 0; kk < 4; ++kk) bf[kk] = ldfrag_f(Kc, kq * 16 + l15, kk, g);
#pragma unroll
            for (int mt = 0; mt < 2; ++mt)
#pragma unroll
                for (int kk = 0; kk < 4; ++kk)
                    acc[nb][mt] = __builtin_amdgcn_mfma_f32_16x16x32_bf16(
                        qf[mt][kk], bf[kk], acc[nb][mt], 0, 0, 0);
            __syncthreads();
            if (nb < 7) {
                stage_write_f(Kb[(nb + 1) & 1], tid, gk);
            } else if (ds < 7) {
                stage_write_f(Kb[0], tid, gk);
                stage_write_f(Qb, tid, gq);
            }
            __syncthreads();
        }
    }
#pragma unroll
    for (int nb = 0; nb < 8; ++nb)
#pragma unroll
        for (int mt = 0; mt < 2; ++mt) {
            f32x4 t = acc[nb][mt];
#pragma unroll
            for (int r = 0; r < 4; ++r) t[r] = __expf(t[r] * 0.03125f);
            acc[nb][mt] = t;
        }
    float rp[2][4];
#pragma unroll
    for (int mt = 0; mt < 2; ++mt)
#pragma unroll
        for (int r = 0; r < 4; ++r) {
            float s = 0.f;
#pragma unroll
            for (int nb = 0; nb < 8; ++nb) s += acc[nb][mt][r];
            rp[mt][r] = s;
        }
#pragma unroll
    for (int m = 1; m <= 8; m <<= 1)
#pragma unroll
        for (int mt = 0; mt < 2; ++mt)
#pragma unroll
            for (int r = 0; r < 4; ++r)
                rp[mt][r] += __shfl_xor(rp[mt][r], m, 64);
    if (l15 == 0) {
#pragma unroll
        for (int mt = 0; mt < 2; ++mt)
#pragma unroll
            for (int r = 0; r < 4; ++r)
                lred[qh * 32 + mt * 16 + g * 4 + r][kq] = rp[mt][r];
    }
    __syncthreads();
    if (tid < 64) {
        float l = lred[tid][0] + lred[tid][1] + lred[tid][2] + lred[tid][3];
        invl[tid] = 1.0f / l;
    }
    __syncthreads();
    float iq[2][4];
#pragma unroll
    for (int mt = 0; mt < 2; ++mt)
#pragma unroll
        for (int r = 0; r < 4; ++r)
            iq[mt][r] = invl[qh * 32 + mt * 16 + g * 4 + r];
#pragma unroll
    for (int nb = 0; nb < 8; ++nb) {
        float cp = 0.f;
#pragma unroll
        for (int mt = 0; mt < 2; ++mt)
#pragma unroll
            for (int r = 0; r < 4; ++r) cp += acc[nb][mt][r] * iq[mt][r];
        cp += __shfl_xor(cp, 16, 64);
        cp += __shfl_xor(cp, 32, 64);
        if (lane < 16) cred[qh][nb * 64 + kq * 16 + lane] = cp;
    }
    __syncthreads();
    c_part[(size_t)blk * 512 + tid] = cred[0][tid] + cred[1][tid];
}
__global__ __launch_bounds__(256) void k2_pool_fb(const float* __restrict__ seq,
                                                  const float* __restrict__ c_part,
                                                  float* __restrict__ pooled_part) {
    const int blk = blockIdx.x;
    const int b = blk >> 2, kt = blk & 3;
    const int tid = threadIdx.x;
    __shared__ float cw[128];
    if (tid < 128) {
        int k = kt * 128 + tid;
        float s = 0.f;
#pragma unroll
        for (int qt = 0; qt < 8; ++qt) s += c_part[(size_t)(qt * 64 + b) * 512 + k];
        cw[tid] = s;
    }
    __syncthreads();
    float a0 = 0.f, a1 = 0.f, a2 = 0.f, a3 = 0.f;
    const float* base = seq + ((size_t)b * SL + kt * 128) * DIM + tid * 4;
    for (int kk = 0; kk < 128; ++kk) {
        float c = cw[kk];
        float4 v = *(const float4*)(base + (size_t)kk * DIM);
        a0 += c * v.x; a1 += c * v.y; a2 += c * v.z; a3 += c * v.w;
    }
    float* dst = pooled_part + (size_t)(b * 4 + kt) * DIM + tid * 4;
    *(float4*)dst = make_float4(a0, a1, a2, a3);
}
// ============================================================================

extern "C" void kernel_launch(void* const* d_in, const int* in_sizes, int n_in,
                              void* d_out, int out_size, void* d_ws, size_t ws_size,
                              hipStream_t stream) {
    const float* seq = (const float*)d_in[0];
    const float* Wm  = (const float*)d_in[1];
    const float* bm  = (const float*)d_in[2];
    const float* Wv  = (const float*)d_in[3];
    const float* bv  = (const float*)d_in[4];
    float* out = (float*)d_out;

    const size_t TBELEMS = (size_t)2048 * RBS;               // padded tiled buf
    const size_t FELEMS  = 512 * 512 + 64 * 4 * DIM + 2 * 8 * 64 * 512;
    const size_t need = TBELEMS * 2 + FELEMS * 4;

    if (ws_size >= need) {
        unsigned short* tbuf = (unsigned short*)d_ws;
        float* c_part      = (float*)((char*)d_ws + TBELEMS * 2);
        float* pooled_part = c_part + 512 * 512;
        float* part        = pooled_part + 64 * 4 * DIM;
        hipLaunchKernelGGL(k0_convert, dim3(2048), dim3(256), 0, stream, seq, tbuf);
        hipLaunchKernelGGL(k1_scores,  dim3(512),  dim3(512), 0, stream, tbuf, c_part);
        hipLaunchKernelGGL(k2_pool,    dim3(256),  dim3(256), 0, stream, tbuf, c_part, pooled_part);
        hipLaunchKernelGGL(k3a_gemm,   dim3(2048), dim3(256), 0, stream, pooled_part,
                           Wm, Wv, part);
        hipLaunchKernelGGL(k3b_reduce, dim3(128),  dim3(256), 0, stream, part,
                           bm, bv, out);
    } else {
        float* c_part      = (float*)d_ws;
        float* pooled_part = c_part + 512 * 512;
        hipLaunchKernelGGL(k1_scores_fb, dim3(512), dim3(512), 0, stream, seq, c_part);
        hipLaunchKernelGGL(k2_pool_fb,   dim3(256), dim3(256), 0, stream, seq, c_part, pooled_part);
        hipLaunchKernelGGL(k3_out,       dim3(128), dim3(256), 0, stream, pooled_part,
                           Wm, bm, Wv, bv, out);
    }
}

// Round 12
// 94.714 us; speedup vs baseline: 1.6526x; 1.0048x over previous
//
#include <hip/hip_runtime.h>
#include <hip/hip_bf16.h>

#define TB 64     // batches
#define SL 512    // MAX_LEN (all sequences full length)
#define DIM 1024  // feature dim
#define LAT 512   // latent dim

// Tiled bf16 row-block stride in ELEMENTS (16 rows x 1024 cols = 16384 + 256 pad).
#define RBS 16640

typedef short short8 __attribute__((ext_vector_type(8)));
typedef unsigned uint4v __attribute__((ext_vector_type(4)));
typedef float f32x4 __attribute__((ext_vector_type(4)));

__device__ inline unsigned bfr(float f) {   // fp32 -> bf16 bits (RNE), low 16
    unsigned u = __builtin_bit_cast(unsigned, f);
    u += 0x7FFFu + ((u >> 16) & 1u);
    return u >> 16;
}
__device__ inline unsigned pk2(float lo, float hi) {   // pack 2 bf16 into u32
    return bfr(lo) | (bfr(hi) << 16);
}

// ============================================================================
// Tiled bf16 layout: T[rb][cb][16][32], rb = row/16 (2048), cb = col/32 (32).
// One 16x32 tile (1KB) == one MFMA A/B fragment. addr = rb*RBS + cb*512 + r*32+c
// ============================================================================

// K0: fp32 row-major -> bf16 tiled. Block g handles rows g*16..g*16+15.
__global__ __launch_bounds__(256) void k0_convert(const float* __restrict__ seq,
                                                  unsigned short* __restrict__ tb) {
    const int gblk = blockIdx.x;          // 2048 row-groups
    const int tid = threadIdx.x;
    const float* src = seq + (size_t)gblk * 16 * DIM;
    unsigned short* dst = tb + (size_t)gblk * RBS;
    const int cb = tid >> 3;              // tile column 0..31
    const int cc = (tid & 7) * 4;         // col within tile
#pragma unroll
    for (int j = 0; j < 16; ++j) {
        float4 v = *(const float4*)(src + (size_t)j * DIM + tid * 4);
        unsigned short* d = dst + cb * 512 + j * 32 + cc;
        uint2 w;
        w.x = pk2(v.x, v.y);
        w.y = pk2(v.z, v.w);
        *(uint2*)d = w;
    }
}

// Async 1KB tile copy: per-lane global src (16B granules), wave-uniform LDS dst.
#define GLDS(srcp, dstp)                                                          \
    __builtin_amdgcn_global_load_lds(                                             \
        (const __attribute__((address_space(1))) void*)(srcp),                    \
        (__attribute__((address_space(3))) void*)(dstp), 16, 0, 0)

// K1 v6: per-(batch, 64-q-row tile) block, 512 threads (8 waves).
// 2-buffer rotation with counted vmcnt (never 0 in the loop) and RAW
// s_barriers. Iteration: vmcnt(4) | bar | COMPUTE | lgkmcnt(0) | bar | STAGE.
// LDS = 2x32KB + 2.3KB -> 2 blocks/CU (4 waves/SIMD).
__global__ __launch_bounds__(512, 4) void k1_scores(const unsigned short* __restrict__ tb,
                                                    float* __restrict__ c_part) {
    const int blk = blockIdx.x;            // 512 = 8 q-tiles * 64 batches
    const int b = blk & 63, qt = blk >> 6; // same-batch tiles co-XCD
    const int tid = threadIdx.x;
    const int w = tid >> 6, lane = tid & 63;
    const int g = lane >> 4, l15 = lane & 15;
    const int qt4 = qt * 4;

    __shared__ __align__(16) unsigned short K_lds[2][32 * 512];  // 2 x 32 KB
    __shared__ float lred[64][8];
    __shared__ float invl[64];

    // staging: lane's swizzled source granule (elems); involution i^(i>>3)
    const int gsw = (lane ^ (lane >> 3)) * 8;
    // reading: swizzled byte offset within a 1KB tile for this lane's fragment
    const int tg = l15 * 4 + g;
    const int roff = (tg ^ (tg >> 3)) * 16;

    const unsigned short* krb = tb + (size_t)(b * 32 + w) * RBS + gsw;  // +nb*8*RBS

    f32x4 acc[4][4];   // [nb][mt]
#pragma unroll
    for (int nb = 0; nb < 4; ++nb)
#pragma unroll
        for (int mt = 0; mt < 4; ++mt) acc[nb][mt] = (f32x4){0.f, 0.f, 0.f, 0.f};

#define STAGE(bufi, ds_) {                                                        \
    _Pragma("unroll") for (int nb = 0; nb < 4; ++nb)                              \
        GLDS(krb + (size_t)(nb * 8) * RBS + (ds_) * 512,                          \
             &K_lds[bufi][(nb * 8 + w) * 512]);                                   \
}
#define COMPUTE(bufi) {                                                           \
    const char* Kc = (const char*)K_lds[bufi];                                    \
    short8 qf[4], kf[4];                                                          \
    _Pragma("unroll") for (int mt = 0; mt < 4; ++mt)                              \
        qf[mt] = *(const short8*)(Kc + (qt4 + mt) * 1024 + roff);                 \
    _Pragma("unroll") for (int nb = 0; nb < 4; ++nb)                              \
        kf[nb] = *(const short8*)(Kc + ((nb << 3) + w) * 1024 + roff);            \
    _Pragma("unroll") for (int nb = 0; nb < 4; ++nb)                              \
        _Pragma("unroll") for (int mt = 0; mt < 4; ++mt)                          \
            acc[nb][mt] = __builtin_amdgcn_mfma_f32_16x16x32_bf16(                \
                qf[mt], kf[nb], acc[nb][mt], 0, 0, 0);                            \
}

    // prologue: stages 0 and 1 in flight (8 outstanding loads/wave)
    STAGE(0, 0);
    STAGE(1, 1);

    for (int ds = 0; ds < 30; ++ds) {
        asm volatile("s_waitcnt vmcnt(4)" ::: "memory");   // my stage-ds loads landed
        __builtin_amdgcn_s_barrier();                      // everyone's landed
        __builtin_amdgcn_sched_barrier(0);
        COMPUTE(ds & 1);                                   // ds_reads + MFMAs
        asm volatile("s_waitcnt lgkmcnt(0)" ::: "memory"); // my LDS reads complete
        __builtin_amdgcn_sched_barrier(0);                 // rule-18 fence
        __builtin_amdgcn_s_barrier();                      // everyone done reading buf
        __builtin_amdgcn_sched_barrier(0);
        STAGE(ds & 1, ds + 2);                             // refill; 8 outstanding
    }
    // ds = 30: outstanding = S30(4)+S31(4); no refill
    asm volatile("s_waitcnt vmcnt(4)" ::: "memory");
    __builtin_amdgcn_s_barrier();
    __builtin_amdgcn_sched_barrier(0);
    COMPUTE(0);
    // ds = 31: outstanding = S31(4)
    asm volatile("s_waitcnt vmcnt(0)" ::: "memory");
    __builtin_amdgcn_s_barrier();
    __builtin_amdgcn_sched_barrier(0);
    COMPUTE(1);
#undef STAGE
#undef COMPUTE

    // exp (scale 1/32); q = mt*16 + g*4 + r, k = nb*128 + w*16 + l15
#pragma unroll
    for (int nb = 0; nb < 4; ++nb)
#pragma unroll
        for (int mt = 0; mt < 4; ++mt) {
            f32x4 t = acc[nb][mt];
#pragma unroll
            for (int r = 0; r < 4; ++r) t[r] = __expf(t[r] * 0.03125f);
            acc[nb][mt] = t;
        }

    // row sums: per-thread over nb, then over the 16-lane l15 group
    float rp[4][4];
#pragma unroll
    for (int mt = 0; mt < 4; ++mt)
#pragma unroll
        for (int r = 0; r < 4; ++r) {
            float s = 0.f;
#pragma unroll
            for (int nb = 0; nb < 4; ++nb) s += acc[nb][mt][r];
            rp[mt][r] = s;
        }
#pragma unroll
    for (int m = 1; m <= 8; m <<= 1)
#pragma unroll
        for (int mt = 0; mt < 4; ++mt)
#pragma unroll
            for (int r = 0; r < 4; ++r)
                rp[mt][r] += __shfl_xor(rp[mt][r], m, 64);
    if (l15 == 0) {
#pragma unroll
        for (int mt = 0; mt < 4; ++mt)
#pragma unroll
            for (int r = 0; r < 4; ++r)
                lred[mt * 16 + g * 4 + r][w] = rp[mt][r];
    }
    __syncthreads();
    if (tid < 64) {
        float l = 0.f;
#pragma unroll
        for (int ww = 0; ww < 8; ++ww) l += lred[tid][ww];
        invl[tid] = 1.0f / l;
    }
    __syncthreads();

    float iq[4][4];
#pragma unroll
    for (int mt = 0; mt < 4; ++mt)
#pragma unroll
        for (int r = 0; r < 4; ++r)
            iq[mt][r] = invl[mt * 16 + g * 4 + r];

    // weighted column sums over this block's 64 q rows
#pragma unroll
    for (int nb = 0; nb < 4; ++nb) {
        float cp = 0.f;
#pragma unroll
        for (int mt = 0; mt < 4; ++mt)
#pragma unroll
            for (int r = 0; r < 4; ++r) cp += acc[nb][mt][r] * iq[mt][r];
        cp += __shfl_xor(cp, 16, 64);
        cp += __shfl_xor(cp, 32, 64);
        if (lane < 16)
            c_part[(size_t)blk * 512 + nb * 128 + w * 16 + lane] = cp;
    }
}

// K2: pooled_part from the bf16 tiled buffer.
__global__ __launch_bounds__(256) void k2_pool(const unsigned short* __restrict__ tb,
                                               const float* __restrict__ c_part,
                                               float* __restrict__ pooled_part) {
    const int blk = blockIdx.x;          // 256 = 64 batches * 4 key-ranges
    const int b = blk >> 2, kt = blk & 3;
    const int tid = threadIdx.x;
    __shared__ float cw[128];
    if (tid < 128) {
        int k = kt * 128 + tid;
        float s = 0.f;
#pragma unroll
        for (int qt = 0; qt < 8; ++qt) s += c_part[(size_t)(qt * 64 + b) * 512 + k];
        cw[tid] = s;
    }
    __syncthreads();
    const int cb = tid >> 3;              // d/32
    const int cc = (tid & 7) * 4;         // d%32
    float a0 = 0.f, a1 = 0.f, a2 = 0.f, a3 = 0.f;
    const unsigned short* base = tb + (size_t)(b * 32 + kt * 8) * RBS + cb * 512 + cc;
    for (int kk = 0; kk < 128; ++kk) {
        float c = cw[kk];
        const unsigned short* p = base + (size_t)(kk >> 4) * RBS + (kk & 15) * 32;
        uint2 u = *(const uint2*)p;
        a0 += c * __builtin_bit_cast(float, u.x << 16);
        a1 += c * __builtin_bit_cast(float, u.x & 0xFFFF0000u);
        a2 += c * __builtin_bit_cast(float, u.y << 16);
        a3 += c * __builtin_bit_cast(float, u.y & 0xFFFF0000u);
    }
    float* dst = pooled_part + (size_t)(b * 4 + kt) * DIM + tid * 4;
    *(float4*)dst = make_float4(a0, a1, a2, a3);
}

// K3 v3 (fused): grid 1024 = b(64) x s(16 W-slices); s = h*8 + lq.
// blk%8 == s%8 -> the 64 blocks sharing a W-slice live on ONE XCD (L2 reuse).
// Per block: stage p[1024] (float4), 16 dgroups x 16 colgroups, each thread
// 64 float4 W loads (16B/lane), LDS-reduce over dgroups, +bias, write.
__global__ __launch_bounds__(256) void k3_fused(const float* __restrict__ pooled_part,
                                                const float* __restrict__ Wm,
                                                const float* __restrict__ Wv,
                                                const float* __restrict__ bm,
                                                const float* __restrict__ bv,
                                                float* __restrict__ out) {
    const int blk = blockIdx.x;          // 1024
    const int s = blk & 15, b = blk >> 4;
    const int h = s >> 3, lq = s & 7;    // head, 64-col latent slice
    const int tid = threadIdx.x;
    const float* W = h ? Wv : Wm;
    __shared__ __align__(16) f32x4 p4[256];     // p[1024]
    __shared__ __align__(16) f32x4 red[16][16]; // [dgrp][colgrp]

    {
        f32x4 a = (f32x4){0.f, 0.f, 0.f, 0.f};
#pragma unroll
        for (int kt = 0; kt < 4; ++kt)
            a += *(const f32x4*)(pooled_part + (size_t)(b * 4 + kt) * DIM + tid * 4);
        p4[tid] = a;
    }
    __syncthreads();

    const float* p = (const float*)p4;
    const int cg = tid & 15;             // colgroup: 4 cols = cols lq*64+cg*4..+3
    const int dg = tid >> 4;             // dgroup: d = dg*64 .. +63
    const float* wb = W + (size_t)(dg * 64) * LAT + lq * 64 + cg * 4;
    f32x4 acc = (f32x4){0.f, 0.f, 0.f, 0.f};
#pragma unroll 8
    for (int dd = 0; dd < 64; ++dd) {
        f32x4 wv = *(const f32x4*)(wb + (size_t)dd * LAT);
        acc += p[dg * 64 + dd] * wv;
    }
    red[dg][cg] = acc;
    __syncthreads();
    if (tid < 16) {
        f32x4 t = red[0][tid];
#pragma unroll
        for (int j = 1; j < 16; ++j) t += red[j][tid];
        const float* bias = h ? bv : bm;
        const int l = lq * 64 + tid * 4;
        t += *(const f32x4*)(bias + l);
        *(f32x4*)(out + (size_t)h * TB * LAT + (size_t)b * LAT + l) = t;
    }
}

// K3 (fallback only): out = pooled @ W + bias for both heads.
__global__ __launch_bounds__(256) void k3_out(const float* __restrict__ pooled_part,
                                              const float* __restrict__ Wm,
                                              const float* __restrict__ bm,
                                              const float* __restrict__ Wv,
                                              const float* __restrict__ bv,
                                              float* __restrict__ out) {
    const int blk = blockIdx.x;          // 128 = 64 batches * 2 heads
    const int b = blk >> 1, which = blk & 1;
    const int tid = threadIdx.x;
    const float* W = which ? Wv : Wm;
    const float* bias = which ? bv : bm;
    __shared__ float p[1024];
#pragma unroll
    for (int i = 0; i < 4; ++i) {
        int d = tid + (i << 8);
        float s = 0.f;
#pragma unroll
        for (int kt = 0; kt < 4; ++kt) s += pooled_part[(size_t)(b * 4 + kt) * DIM + d];
        p[d] = s;
    }
    __syncthreads();
    float acc0 = bias[tid], acc1 = bias[tid + 256];
    for (int d = 0; d < 1024; ++d) {
        float pv = p[d];
        const float* wr = W + (size_t)d * LAT;
        acc0 += pv * wr[tid];
        acc1 += pv * wr[tid + 256];
    }
    float* o = out + (size_t)which * TB * LAT + (size_t)b * LAT;
    o[tid] = acc0;
    o[tid + 256] = acc1;
}

// ============================ fallback path (round-3) =======================
__device__ inline short8 ldfrag_f(const char* lds, int row, int kk, int g) {
    int byte = (row * 256 + kk * 64 + (g << 4)) ^ ((row & 7) << 4);
    return *(const short8*)(lds + byte);
}
__device__ inline void stage_load_f(const float* src, float4* gg) {
    gg[0] = *(const float4*)(src);
    gg[1] = *(const float4*)(src + 4);
    gg[2] = *(const float4*)(src + 8);
    gg[3] = *(const float4*)(src + 12);
}
__device__ inline void stage_write_f(char* lds, int t, const float4* gg) {
    int r = t >> 3;
    int x0 = (t & 7) * 32;
    int sw = (r & 7) << 4;
    uint4v w0, w1;
    w0[0] = pk2(gg[0].x, gg[0].y); w0[1] = pk2(gg[0].z, gg[0].w);
    w0[2] = pk2(gg[1].x, gg[1].y); w0[3] = pk2(gg[1].z, gg[1].w);
    w1[0] = pk2(gg[2].x, gg[2].y); w1[1] = pk2(gg[2].z, gg[2].w);
    w1[2] = pk2(gg[3].x, gg[3].y); w1[3] = pk2(gg[3].z, gg[3].w);
    *(uint4v*)(lds + ((r * 256 + x0) ^ sw))      = w0;
    *(uint4v*)(lds + ((r * 256 + x0 + 16) ^ sw)) = w1;
}
__global__ __launch_bounds__(512, 2) void k1_scores_fb(const float* __restrict__ seq,
                                                       float* __restrict__ c_part) {
    const int blk = blockIdx.x;
    const int b = blk & 63, qt = blk >> 6;
    const int tid = threadIdx.x;
    const int wave = tid >> 6, lane = tid & 63;
    const int qh = wave >> 2, kq = wave & 3;
    const int g = lane >> 4, l15 = lane & 15;
    __shared__ __align__(16) char Qb[16384];
    __shared__ __align__(16) char Kb[2][16384];
    __shared__ float lred[64][4];
    __shared__ float invl[64];
    __shared__ float cred[2][512];
    const float* qbase = seq + (size_t)(b * SL + qt * 64) * DIM;
    const float* kbase = seq + (size_t)(b * SL) * DIM;
    const int sr = tid >> 3;
    const int sx = (tid & 7) * 16;
    f32x4 acc[8][2];
#pragma unroll
    for (int nb = 0; nb < 8; ++nb)
#pragma unroll
        for (int mt = 0; mt < 2; ++mt) acc[nb][mt] = (f32x4){0.f, 0.f, 0.f, 0.f};
    {
        float4 gq[4], gk[4];
        stage_load_f(qbase + (size_t)sr * DIM + sx, gq);
        stage_load_f(kbase + (size_t)sr * DIM + sx, gk);
        stage_write_f(Qb, tid, gq);
        stage_write_f(Kb[0], tid, gk);
        __syncthreads();
    }
    for (int ds = 0; ds < 8; ++ds) {
        short8 qf[2][4];
#pragma unroll
        for (int mt = 0; mt < 2; ++mt)
#pragma unroll
            for (int kk = 0; kk < 4; ++kk)
                qf[mt][kk] = ldfrag_f(Qb, qh * 32 + mt * 16 + l15, kk, g);
#pragma unroll
        for (int nb = 0; nb < 8; ++nb) {
            const char* Kc = Kb[nb & 1];
            float4 gk[4], gq[4];
            if (nb < 7) {
                stage_load_f(kbase + (size_t)((nb + 1) * 64 + sr) * DIM + ds * 128 + sx, gk);
            } else if (ds < 7) {
                stage_load_f(kbase + (size_t)sr * DIM + (ds + 1) * 128 + sx, gk);
                stage_load_f(qbase + (size_t)sr * DIM + (ds + 1) * 128 + sx, gq);
            }
            short8 bf[4];
#pragma unroll
            for (int kk = 0; kk < 4; ++kk) bf[kk] = ldfrag_f(Kc, kq * 16 + l15, kk, g);
#pragma unroll
            for (int mt = 0; mt < 2; ++mt)
#pragma unroll
                for (int kk = 0; kk < 4; ++kk)
                    acc[nb][mt] = __builtin_amdgcn_mfma_f32_16x16x32_bf16(
                        qf[mt][kk], bf[kk], acc[nb][mt], 0, 0, 0);
            __syncthreads();
            if (nb < 7) {
                stage_write_f(Kb[(nb + 1) & 1], tid, gk);
            } else if (ds < 7) {
                stage_write_f(Kb[0], tid, gk);
                stage_write_f(Qb, tid, gq);
            }
            __syncthreads();
        }
    }
#pragma unroll
    for (int nb = 0; nb < 8; ++nb)
#pragma unroll
        for (int mt = 0; mt < 2; ++mt) {
            f32x4 t = acc[nb][mt];
#pragma unroll
            for (int r = 0; r < 4; ++r) t[r] = __expf(t[r] * 0.03125f);
            acc[nb][mt] = t;
        }
    float rp[2][4];
#pragma unroll
    for (int mt = 0; mt < 2; ++mt)
#pragma unroll
        for (int r = 0; r < 4; ++r) {
            float s = 0.f;
#pragma unroll
            for (int nb = 0; nb < 8; ++nb) s += acc[nb][mt][r];
            rp[mt][r] = s;
        }
#pragma unroll
    for (int m = 1; m <= 8; m <<= 1)
#pragma unroll
        for (int mt = 0; mt < 2; ++mt)
#pragma unroll
            for (int r = 0; r < 4; ++r)
                rp[mt][r] += __shfl_xor(rp[mt][r], m, 64);
    if (l15 == 0) {
#pragma unroll
        for (int mt = 0; mt < 2; ++mt)
#pragma unroll
            for (int r = 0; r < 4; ++r)
                lred[qh * 32 + mt * 16 + g * 4 + r][kq] = rp[mt][r];
    }
    __syncthreads();
    if (tid < 64) {
        float l = lred[tid][0] + lred[tid][1] + lred[tid][2] + lred[tid][3];
        invl[tid] = 1.0f / l;
    }
    __syncthreads();
    float iq[2][4];
#pragma unroll
    for (int mt = 0; mt < 2; ++mt)
#pragma unroll
        for (int r = 0; r < 4; ++r)
            iq[mt][r] = invl[qh * 32 + mt * 16 + g * 4 + r];
#pragma unroll
    for (int nb = 0; nb < 8; ++nb) {
        float cp = 0.f;
#pragma unroll
        for (int mt = 0; mt < 2; ++mt)
#pragma unroll
            for (int r = 0; r < 4; ++r) cp += acc[nb][mt][r] * iq[mt][r];
        cp += __shfl_xor(cp, 16, 64);
        cp += __shfl_xor(cp, 32, 64);
        if (lane < 16) cred[qh][nb * 64 + kq * 16 + lane] = cp;
    }
    __syncthreads();
    c_part[(size_t)blk * 512 + tid] = cred[0][tid] + cred[1][tid];
}
__global__ __launch_bounds__(256) void k2_pool_fb(const float* __restrict__ seq,
                                                  const float* __restrict__ c_part,
                                                  float* __restrict__ pooled_part) {
    const int blk = blockIdx.x;
    const int b = blk >> 2, kt = blk & 3;
    const int tid = threadIdx.x;
    __shared__ float cw[128];
    if (tid < 128) {
        int k = kt * 128 + tid;
        float s = 0.f;
#pragma unroll
        for (int qt = 0; qt < 8; ++qt) s += c_part[(size_t)(qt * 64 + b) * 512 + k];
        cw[tid] = s;
    }
    __syncthreads();
    float a0 = 0.f, a1 = 0.f, a2 = 0.f, a3 = 0.f;
    const float* base = seq + ((size_t)b * SL + kt * 128) * DIM + tid * 4;
    for (int kk = 0; kk < 128; ++kk) {
        float c = cw[kk];
        float4 v = *(const float4*)(base + (size_t)kk * DIM);
        a0 += c * v.x; a1 += c * v.y; a2 += c * v.z; a3 += c * v.w;
    }
    float* dst = pooled_part + (size_t)(b * 4 + kt) * DIM + tid * 4;
    *(float4*)dst = make_float4(a0, a1, a2, a3);
}
// ============================================================================

extern "C" void kernel_launch(void* const* d_in, const int* in_sizes, int n_in,
                              void* d_out, int out_size, void* d_ws, size_t ws_size,
                              hipStream_t stream) {
    const float* seq = (const float*)d_in[0];
    const float* Wm  = (const float*)d_in[1];
    const float* bm  = (const float*)d_in[2];
    const float* Wv  = (const float*)d_in[3];
    const float* bv  = (const float*)d_in[4];
    float* out = (float*)d_out;

    const size_t TBELEMS = (size_t)2048 * RBS;               // padded tiled buf
    const size_t FELEMS  = 512 * 512 + 64 * 4 * DIM;
    const size_t need = TBELEMS * 2 + FELEMS * 4;

    if (ws_size >= need) {
        unsigned short* tbuf = (unsigned short*)d_ws;
        float* c_part      = (float*)((char*)d_ws + TBELEMS * 2);
        float* pooled_part = c_part + 512 * 512;
        hipLaunchKernelGGL(k0_convert, dim3(2048), dim3(256), 0, stream, seq, tbuf);
        hipLaunchKernelGGL(k1_scores,  dim3(512),  dim3(512), 0, stream, tbuf, c_part);
        hipLaunchKernelGGL(k2_pool,    dim3(256),  dim3(256), 0, stream, tbuf, c_part, pooled_part);
        hipLaunchKernelGGL(k3_fused,   dim3(1024), dim3(256), 0, stream, pooled_part,
                           Wm, Wv, bm, bv, out);
    } else {
        float* c_part      = (float*)d_ws;
        float* pooled_part = c_part + 512 * 512;
        hipLaunchKernelGGL(k1_scores_fb, dim3(512), dim3(512), 0, stream, seq, c_part);
        hipLaunchKernelGGL(k2_pool_fb,   dim3(256), dim3(256), 0, stream, seq, c_part, pooled_part);
        hipLaunchKernelGGL(k3_out,       dim3(128), dim3(256), 0, stream, pooled_part,
                           Wm, bm, Wv, bv, out);
    }
}

// Round 13
// 91.533 us; speedup vs baseline: 1.7100x; 1.0348x over previous
//
#include <hip/hip_runtime.h>
#include <hip/hip_bf16.h>

#define TB 64     // batches
#define SL 512    // MAX_LEN (all sequences full length)
#define DIM 1024  // feature dim
#define LAT 512   // latent dim

// fp8 tiled row-block stride in BYTES: 32 tiles x 512 B = 16384 + 256 pad.
#define RBS8 16640

typedef short short8 __attribute__((ext_vector_type(8)));
typedef unsigned uint4v __attribute__((ext_vector_type(4)));
typedef float f32x4 __attribute__((ext_vector_type(4)));

__device__ inline unsigned bfr(float f) {   // fp32 -> bf16 bits (RNE), low 16
    unsigned u = __builtin_bit_cast(unsigned, f);
    u += 0x7FFFu + ((u >> 16) & 1u);
    return u >> 16;
}
__device__ inline unsigned pk2(float lo, float hi) {   // pack 2 bf16 into u32
    return bfr(lo) | (bfr(hi) << 16);
}

// fp32 -> OCP e4m3fn (RNE, flush-to-zero below 2^-6, sat 448). Exact enough:
// per-element rel err ~6% leaves softmax weights (gap >= 22 in exponent)
// unchanged to ~1e-7 — see analysis in the round notes.
__device__ inline unsigned f2fp8(float f) {
    unsigned u = __builtin_bit_cast(unsigned, f);
    unsigned s = (u >> 31) << 7;
    int e = (u >> 23) & 255;
    unsigned m = u & 0x7FFFFFu;
    if (e < 121) return s;                       // |x| < 2^-6 -> 0
    unsigned t = ((unsigned)(e - 120) << 3) | (m >> 20);
    unsigned frac = m & 0xFFFFFu;
    t += (frac > 0x80000u) || (frac == 0x80000u && (t & 1u));
    if (t > 0x7Eu) t = 0x7Eu;                    // sat to 448, avoid NaN
    return s | t;
}

// ============================================================================
// fp8 tiled layout: T8[rb][cb][16][32] bytes, rb = row/16 (2048), cb = col/32.
// One 16x32 fp8 tile (512 B) == one mfma_16x16x32_fp8 A/B fragment:
// lane l reads 8 B at (l&15)*32 + (l>>4)*8 (bank-swizzled, see k1).
// addr = rb*RBS8 + cb*512 + r*32 + c
// ============================================================================

// K0': fp32 row-major -> fp8 tiled. Block g handles rows g*16..g*16+15.
__global__ __launch_bounds__(256) void k0_fp8(const float* __restrict__ seq,
                                              unsigned char* __restrict__ t8) {
    const int gblk = blockIdx.x;          // 2048 row-groups
    const int tid = threadIdx.x;
    const float* src = seq + (size_t)gblk * 16 * DIM;
    unsigned char* dst = t8 + (size_t)gblk * RBS8;
    const int cb = tid >> 3;              // tile column 0..31
    const int cc = (tid & 7) * 4;         // byte offset within 32-B row
#pragma unroll
    for (int j = 0; j < 16; ++j) {
        float4 v = *(const float4*)(src + (size_t)j * DIM + tid * 4);
        unsigned p = f2fp8(v.x) | (f2fp8(v.y) << 8) |
                     (f2fp8(v.z) << 16) | (f2fp8(v.w) << 24);
        *(unsigned*)(dst + cb * 512 + j * 32 + cc) = p;
    }
}

// Async 16B/lane tile copy: per-lane global src, wave-uniform LDS dst.
#define GLDS(srcp, dstp)                                                          \
    __builtin_amdgcn_global_load_lds(                                             \
        (const __attribute__((address_space(1))) void*)(srcp),                    \
        (__attribute__((address_space(3))) void*)(dstp), 16, 0, 0)

// K1': per-(batch, 64-q-row tile) block, 512 threads (8 waves), fp8 MFMA.
// Wave w owns k cols {nb*128 + w*16}; Q fragments read from the same staged
// data (row-groups qt*4+mt). 16 superstages of 64 features (2 fp8 tiles =
// 1 KB per row-group), 2-buffer rotation, counted vmcnt(4) (never 0 in the
// loop), raw s_barriers. Granule(8B) swizzle sigma(r)=((r>>2)&1)<<1 applied
// to BOTH the GLDS source and the ds_read_b64 address -> 2-way (free) banks.
__global__ __launch_bounds__(512, 4) void k1_fp8(const unsigned char* __restrict__ t8,
                                                 float* __restrict__ c_part) {
    const int blk = blockIdx.x;            // 512 = 8 q-tiles * 64 batches
    const int b = blk & 63, qt = blk >> 6; // same-batch tiles co-XCD
    const int tid = threadIdx.x;
    const int w = tid >> 6, lane = tid & 63;
    const int g = lane >> 4, l15 = lane & 15;
    const int qt4 = qt * 4;

    __shared__ __align__(16) unsigned char K_lds[2][32 * 1024];  // 2 x 32 KB
    __shared__ float lred[64][8];
    __shared__ float invl[64];

    // ds_read swizzled offset: frag (row r=l15, k-chunk g) at r*32 + (g^sig)*8
    const int rdoff = l15 * 32 + ((g ^ (((l15 >> 2) & 1) << 1)) << 3);
    // staging pre-swizzled source offset (lane covers 16 B = 2 granules)
    const int tt = lane >> 5, lt = lane & 31;
    const int rr = lt >> 1, gp = (lane & 1) << 1;
    const int sg = ((rr >> 2) & 1) << 1;
    const int srcoff = tt * 512 + rr * 32 + ((gp ^ sg) << 3);

    const unsigned char* krb8 = t8 + (size_t)(b * 32 + w) * RBS8 + srcoff;

    f32x4 acc[4][4];   // [nb][mt]
#pragma unroll
    for (int nb = 0; nb < 4; ++nb)
#pragma unroll
        for (int mt = 0; mt < 4; ++mt) acc[nb][mt] = (f32x4){0.f, 0.f, 0.f, 0.f};

#define STAGE(bufi, ss_) {                                                        \
    _Pragma("unroll") for (int nb = 0; nb < 4; ++nb)                              \
        GLDS(krb8 + (size_t)(nb * 8) * RBS8 + (ss_) * 1024,                       \
             (unsigned char*)K_lds[bufi] + ((nb << 3) + w) * 1024);               \
}
#define COMPUTE(bufi) {                                                           \
    const char* Kc = (const char*)K_lds[bufi];                                    \
    _Pragma("unroll") for (int ch = 0; ch < 2; ++ch) {                            \
        long qf[4], kf[4];                                                        \
        _Pragma("unroll") for (int mt = 0; mt < 4; ++mt)                          \
            qf[mt] = *(const long*)(Kc + (qt4 + mt) * 1024 + ch * 512 + rdoff);   \
        _Pragma("unroll") for (int nb = 0; nb < 4; ++nb)                          \
            kf[nb] = *(const long*)(Kc + ((nb << 3) + w) * 1024 + ch * 512 + rdoff); \
        _Pragma("unroll") for (int nb = 0; nb < 4; ++nb)                          \
            _Pragma("unroll") for (int mt = 0; mt < 4; ++mt)                      \
                acc[nb][mt] = __builtin_amdgcn_mfma_f32_16x16x32_fp8_fp8(         \
                    qf[mt], kf[nb], acc[nb][mt], 0, 0, 0);                        \
    }                                                                             \
}

    // prologue: superstages 0 and 1 in flight (8 outstanding loads/wave)
    STAGE(0, 0);
    STAGE(1, 1);

    for (int ss = 0; ss < 14; ++ss) {
        asm volatile("s_waitcnt vmcnt(4)" ::: "memory");   // my stage-ss landed
        __builtin_amdgcn_s_barrier();                      // everyone's landed
        __builtin_amdgcn_sched_barrier(0);
        COMPUTE(ss & 1);
        asm volatile("s_waitcnt lgkmcnt(0)" ::: "memory"); // my LDS reads done
        __builtin_amdgcn_sched_barrier(0);
        __builtin_amdgcn_s_barrier();                      // everyone done reading
        __builtin_amdgcn_sched_barrier(0);
        STAGE(ss & 1, ss + 2);                             // refill; 8 outstanding
    }
    asm volatile("s_waitcnt vmcnt(4)" ::: "memory");
    __builtin_amdgcn_s_barrier();
    __builtin_amdgcn_sched_barrier(0);
    COMPUTE(0);   // ss = 14
    asm volatile("s_waitcnt vmcnt(0)" ::: "memory");
    __builtin_amdgcn_s_barrier();
    __builtin_amdgcn_sched_barrier(0);
    COMPUTE(1);   // ss = 15
#undef STAGE
#undef COMPUTE

    // exp (scale 1/32); q = mt*16 + g*4 + r, k = nb*128 + w*16 + l15
#pragma unroll
    for (int nb = 0; nb < 4; ++nb)
#pragma unroll
        for (int mt = 0; mt < 4; ++mt) {
            f32x4 t = acc[nb][mt];
#pragma unroll
            for (int r = 0; r < 4; ++r) t[r] = __expf(t[r] * 0.03125f);
            acc[nb][mt] = t;
        }

    // row sums: per-thread over nb, then over the 16-lane l15 group
    float rp[4][4];
#pragma unroll
    for (int mt = 0; mt < 4; ++mt)
#pragma unroll
        for (int r = 0; r < 4; ++r) {
            float s = 0.f;
#pragma unroll
            for (int nb = 0; nb < 4; ++nb) s += acc[nb][mt][r];
            rp[mt][r] = s;
        }
#pragma unroll
    for (int m = 1; m <= 8; m <<= 1)
#pragma unroll
        for (int mt = 0; mt < 4; ++mt)
#pragma unroll
            for (int r = 0; r < 4; ++r)
                rp[mt][r] += __shfl_xor(rp[mt][r], m, 64);
    if (l15 == 0) {
#pragma unroll
        for (int mt = 0; mt < 4; ++mt)
#pragma unroll
            for (int r = 0; r < 4; ++r)
                lred[mt * 16 + g * 4 + r][w] = rp[mt][r];
    }
    __syncthreads();
    if (tid < 64) {
        float l = 0.f;
#pragma unroll
        for (int ww = 0; ww < 8; ++ww) l += lred[tid][ww];
        invl[tid] = 1.0f / l;
    }
    __syncthreads();

    float iq[4][4];
#pragma unroll
    for (int mt = 0; mt < 4; ++mt)
#pragma unroll
        for (int r = 0; r < 4; ++r)
            iq[mt][r] = invl[mt * 16 + g * 4 + r];

    // weighted column sums over this block's 64 q rows
#pragma unroll
    for (int nb = 0; nb < 4; ++nb) {
        float cp = 0.f;
#pragma unroll
        for (int mt = 0; mt < 4; ++mt)
#pragma unroll
            for (int r = 0; r < 4; ++r) cp += acc[nb][mt][r] * iq[mt][r];
        cp += __shfl_xor(cp, 16, 64);
        cp += __shfl_xor(cp, 32, 64);
        if (lane < 16)
            c_part[(size_t)blk * 512 + nb * 128 + w * 16 + lane] = cp;
    }
}

// K2 (fp32, coalesced float4): pooled_part[(b*4+kt)][d] = sum c[k]*ctx[b,k,d]
__global__ __launch_bounds__(256) void k2_pool_f32(const float* __restrict__ seq,
                                                   const float* __restrict__ c_part,
                                                   float* __restrict__ pooled_part) {
    const int blk = blockIdx.x;          // 256 = 64 batches * 4 key-ranges
    const int b = blk >> 2, kt = blk & 3;
    const int tid = threadIdx.x;
    __shared__ float cw[128];
    if (tid < 128) {
        int k = kt * 128 + tid;
        float s = 0.f;
#pragma unroll
        for (int qt = 0; qt < 8; ++qt) s += c_part[(size_t)(qt * 64 + b) * 512 + k];
        cw[tid] = s;
    }
    __syncthreads();
    float a0 = 0.f, a1 = 0.f, a2 = 0.f, a3 = 0.f;
    const float* base = seq + ((size_t)b * SL + kt * 128) * DIM + tid * 4;
    for (int kk = 0; kk < 128; ++kk) {
        float c = cw[kk];
        float4 v = *(const float4*)(base + (size_t)kk * DIM);
        a0 += c * v.x; a1 += c * v.y; a2 += c * v.z; a3 += c * v.w;
    }
    float* dst = pooled_part + (size_t)(b * 4 + kt) * DIM + tid * 4;
    *(float4*)dst = make_float4(a0, a1, a2, a3);
}

// K3 (fused): grid 1024 = b(64) x s(16 W-slices); s = h*8 + lq.
// blk%8 == s%8 -> the 64 blocks sharing a W-slice live on ONE XCD (L2 reuse).
__global__ __launch_bounds__(256) void k3_fused(const float* __restrict__ pooled_part,
                                                const float* __restrict__ Wm,
                                                const float* __restrict__ Wv,
                                                const float* __restrict__ bm,
                                                const float* __restrict__ bv,
                                                float* __restrict__ out) {
    const int blk = blockIdx.x;          // 1024
    const int s = blk & 15, b = blk >> 4;
    const int h = s >> 3, lq = s & 7;    // head, 64-col latent slice
    const int tid = threadIdx.x;
    const float* W = h ? Wv : Wm;
    __shared__ __align__(16) f32x4 p4[256];     // p[1024]
    __shared__ __align__(16) f32x4 red[16][16]; // [dgrp][colgrp]

    {
        f32x4 a = (f32x4){0.f, 0.f, 0.f, 0.f};
#pragma unroll
        for (int kt = 0; kt < 4; ++kt)
            a += *(const f32x4*)(pooled_part + (size_t)(b * 4 + kt) * DIM + tid * 4);
        p4[tid] = a;
    }
    __syncthreads();

    const float* p = (const float*)p4;
    const int cg = tid & 15;             // colgroup: cols lq*64+cg*4..+3
    const int dg = tid >> 4;             // dgroup: d = dg*64 .. +63
    const float* wb = W + (size_t)(dg * 64) * LAT + lq * 64 + cg * 4;
    f32x4 acc = (f32x4){0.f, 0.f, 0.f, 0.f};
#pragma unroll 8
    for (int dd = 0; dd < 64; ++dd) {
        f32x4 wv = *(const f32x4*)(wb + (size_t)dd * LAT);
        acc += p[dg * 64 + dd] * wv;
    }
    red[dg][cg] = acc;
    __syncthreads();
    if (tid < 16) {
        f32x4 t = red[0][tid];
#pragma unroll
        for (int j = 1; j < 16; ++j) t += red[j][tid];
        const float* bias = h ? bv : bm;
        const int l = lq * 64 + tid * 4;
        t += *(const f32x4*)(bias + l);
        *(f32x4*)(out + (size_t)h * TB * LAT + (size_t)b * LAT + l) = t;
    }
}

// ============================ fallback path (round-3, proven) ===============
__device__ inline short8 ldfrag_f(const char* lds, int row, int kk, int g) {
    int byte = (row * 256 + kk * 64 + (g << 4)) ^ ((row & 7) << 4);
    return *(const short8*)(lds + byte);
}
__device__ inline void stage_load_f(const float* src, float4* gg) {
    gg[0] = *(const float4*)(src);
    gg[1] = *(const float4*)(src + 4);
    gg[2] = *(const float4*)(src + 8);
    gg[3] = *(const float4*)(src + 12);
}
__device__ inline void stage_write_f(char* lds, int t, const float4* gg) {
    int r = t >> 3;
    int x0 = (t & 7) * 32;
    int sw = (r & 7) << 4;
    uint4v w0, w1;
    w0[0] = pk2(gg[0].x, gg[0].y); w0[1] = pk2(gg[0].z, gg[0].w);
    w0[2] = pk2(gg[1].x, gg[1].y); w0[3] = pk2(gg[1].z, gg[1].w);
    w1[0] = pk2(gg[2].x, gg[2].y); w1[1] = pk2(gg[2].z, gg[2].w);
    w1[2] = pk2(gg[3].x, gg[3].y); w1[3] = pk2(gg[3].z, gg[3].w);
    *(uint4v*)(lds + ((r * 256 + x0) ^ sw))      = w0;
    *(uint4v*)(lds + ((r * 256 + x0 + 16) ^ sw)) = w1;
}
__global__ __launch_bounds__(512, 2) void k1_scores_fb(const float* __restrict__ seq,
                                                       float* __restrict__ c_part) {
    const int blk = blockIdx.x;
    const int b = blk & 63, qt = blk >> 6;
    const int tid = threadIdx.x;
    const int wave = tid >> 6, lane = tid & 63;
    const int qh = wave >> 2, kq = wave & 3;
    const int g = lane >> 4, l15 = lane & 15;
    __shared__ __align__(16) char Qb[16384];
    __shared__ __align__(16) char Kb[2][16384];
    __shared__ float lred[64][4];
    __shared__ float invl[64];
    __shared__ float cred[2][512];
    const float* qbase = seq + (size_t)(b * SL + qt * 64) * DIM;
    const float* kbase = seq + (size_t)(b * SL) * DIM;
    const int sr = tid >> 3;
    const int sx = (tid & 7) * 16;
    f32x4 acc[8][2];
#pragma unroll
    for (int nb = 0; nb < 8; ++nb)
#pragma unroll
        for (int mt = 0; mt < 2; ++mt) acc[nb][mt] = (f32x4){0.f, 0.f, 0.f, 0.f};
    {
        float4 gq[4], gk[4];
        stage_load_f(qbase + (size_t)sr * DIM + sx, gq);
        stage_load_f(kbase + (size_t)sr * DIM + sx, gk);
        stage_write_f(Qb, tid, gq);
        stage_write_f(Kb[0], tid, gk);
        __syncthreads();
    }
    for (int ds = 0; ds < 8; ++ds) {
        short8 qf[2][4];
#pragma unroll
        for (int mt = 0; mt < 2; ++mt)
#pragma unroll
            for (int kk = 0; kk < 4; ++kk)
                qf[mt][kk] = ldfrag_f(Qb, qh * 32 + mt * 16 + l15, kk, g);
#pragma unroll
        for (int nb = 0; nb < 8; ++nb) {
            const char* Kc = Kb[nb & 1];
            float4 gk[4], gq[4];
            if (nb < 7) {
                stage_load_f(kbase + (size_t)((nb + 1) * 64 + sr) * DIM + ds * 128 + sx, gk);
            } else if (ds < 7) {
                stage_load_f(kbase + (size_t)sr * DIM + (ds + 1) * 128 + sx, gk);
                stage_load_f(qbase + (size_t)sr * DIM + (ds + 1) * 128 + sx, gq);
            }
            short8 bf[4];
#pragma unroll
            for (int kk = 0; kk < 4; ++kk) bf[kk] = ldfrag_f(Kc, kq * 16 + l15, kk, g);
#pragma unroll
            for (int mt = 0; mt < 2; ++mt)
#pragma unroll
                for (int kk = 0; kk < 4; ++kk)
                    acc[nb][mt] = __builtin_amdgcn_mfma_f32_16x16x32_bf16(
                        qf[mt][kk], bf[kk], acc[nb][mt], 0, 0, 0);
            __syncthreads();
            if (nb < 7) {
                stage_write_f(Kb[(nb + 1) & 1], tid, gk);
            } else if (ds < 7) {
                stage_write_f(Kb[0], tid, gk);
                stage_write_f(Qb, tid, gq);
            }
            __syncthreads();
        }
    }
#pragma unroll
    for (int nb = 0; nb < 8; ++nb)
#pragma unroll
        for (int mt = 0; mt < 2; ++mt) {
            f32x4 t = acc[nb][mt];
#pragma unroll
            for (int r = 0; r < 4; ++r) t[r] = __expf(t[r] * 0.03125f);
            acc[nb][mt] = t;
        }
    float rp[2][4];
#pragma unroll
    for (int mt = 0; mt < 2; ++mt)
#pragma unroll
        for (int r = 0; r < 4; ++r) {
            float s = 0.f;
#pragma unroll
            for (int nb = 0; nb < 8; ++nb) s += acc[nb][mt][r];
            rp[mt][r] = s;
        }
#pragma unroll
    for (int m = 1; m <= 8; m <<= 1)
#pragma unroll
        for (int mt = 0; mt < 2; ++mt)
#pragma unroll
            for (int r = 0; r < 4; ++r)
                rp[mt][r] += __shfl_xor(rp[mt][r], m, 64);
    if (l15 == 0) {
#pragma unroll
        for (int mt = 0; mt < 2; ++mt)
#pragma unroll
            for (int r = 0; r < 4; ++r)
                lred[qh * 32 + mt * 16 + g * 4 + r][kq] = rp[mt][r];
    }
    __syncthreads();
    if (tid < 64) {
        float l = lred[tid][0] + lred[tid][1] + lred[tid][2] + lred[tid][3];
        invl[tid] = 1.0f / l;
    }
    __syncthreads();
    float iq[2][4];
#pragma unroll
    for (int mt = 0; mt < 2; ++mt)
#pragma unroll
        for (int r = 0; r < 4; ++r)
            iq[mt][r] = invl[qh * 32 + mt * 16 + g * 4 + r];
#pragma unroll
    for (int nb = 0; nb < 8; ++nb) {
        float cp = 0.f;
#pragma unroll
        for (int mt = 0; mt < 2; ++mt)
#pragma unroll
            for (int r = 0; r < 4; ++r) cp += acc[nb][mt][r] * iq[mt][r];
        cp += __shfl_xor(cp, 16, 64);
        cp += __shfl_xor(cp, 32, 64);
        if (lane < 16) cred[qh][nb * 64 + kq * 16 + lane] = cp;
    }
    __syncthreads();
    c_part[(size_t)blk * 512 + tid] = cred[0][tid] + cred[1][tid];
}
__global__ __launch_bounds__(256) void k3_out(const float* __restrict__ pooled_part,
                                              const float* __restrict__ Wm,
                                              const float* __restrict__ bm,
                                              const float* __restrict__ Wv,
                                              const float* __restrict__ bv,
                                              float* __restrict__ out) {
    const int blk = blockIdx.x;
    const int b = blk >> 1, which = blk & 1;
    const int tid = threadIdx.x;
    const float* W = which ? Wv : Wm;
    const float* bias = which ? bv : bm;
    __shared__ float p[1024];
#pragma unroll
    for (int i = 0; i < 4; ++i) {
        int d = tid + (i << 8);
        float s = 0.f;
#pragma unroll
        for (int kt = 0; kt < 4; ++kt) s += pooled_part[(size_t)(b * 4 + kt) * DIM + d];
        p[d] = s;
    }
    __syncthreads();
    float acc0 = bias[tid], acc1 = bias[tid + 256];
    for (int d = 0; d < 1024; ++d) {
        float pv = p[d];
        const float* wr = W + (size_t)d * LAT;
        acc0 += pv * wr[tid];
        acc1 += pv * wr[tid + 256];
    }
    float* o = out + (size_t)which * TB * LAT + (size_t)b * LAT;
    o[tid] = acc0;
    o[tid + 256] = acc1;
}
// ============================================================================

extern "C" void kernel_launch(void* const* d_in, const int* in_sizes, int n_in,
                              void* d_out, int out_size, void* d_ws, size_t ws_size,
                              hipStream_t stream) {
    const float* seq = (const float*)d_in[0];
    const float* Wm  = (const float*)d_in[1];
    const float* bm  = (const float*)d_in[2];
    const float* Wv  = (const float*)d_in[3];
    const float* bv  = (const float*)d_in[4];
    float* out = (float*)d_out;

    const size_t T8SZ = (size_t)2048 * RBS8;                 // fp8 tiled buf bytes
    const size_t FELEMS = 512 * 512 + 64 * 4 * DIM;          // c_part + pooled
    const size_t need = T8SZ + FELEMS * 4;

    if (ws_size >= need) {
        unsigned char* t8  = (unsigned char*)d_ws;
        float* c_part      = (float*)((char*)d_ws + T8SZ);
        float* pooled_part = c_part + 512 * 512;
        hipLaunchKernelGGL(k0_fp8,      dim3(2048), dim3(256), 0, stream, seq, t8);
        hipLaunchKernelGGL(k1_fp8,      dim3(512),  dim3(512), 0, stream, t8, c_part);
        hipLaunchKernelGGL(k2_pool_f32, dim3(256),  dim3(256), 0, stream, seq, c_part, pooled_part);
        hipLaunchKernelGGL(k3_fused,    dim3(1024), dim3(256), 0, stream, pooled_part,
                           Wm, Wv, bm, bv, out);
    } else {
        float* c_part      = (float*)d_ws;
        float* pooled_part = c_part + 512 * 512;
        hipLaunchKernelGGL(k1_scores_fb, dim3(512), dim3(512), 0, stream, seq, c_part);
        hipLaunchKernelGGL(k2_pool_f32,  dim3(256), dim3(256), 0, stream, seq, c_part, pooled_part);
        hipLaunchKernelGGL(k3_out,       dim3(128), dim3(256), 0, stream, pooled_part,
                           Wm, bm, Wv, bv, out);
    }
}